// Round 11
// baseline (2494.744 us; speedup 1.0000x reference)
//
#include <hip/hip_runtime.h>

// ---------------------------------------------------------------------------
// Petri_GCN: 3x GCNConv(64->64) + MLP readout (64->32->1) + segment-mean pool
// All fp32 (abs threshold forbids bf16/MFMA; no fp32 MFMA on CDNA4).
// R1: CSR-by-dst + gather instead of atomic scatter.
// R2: readout wave-segmented atomics; gather 4x(16-lane x float4) layout.
// R3: count-only atomic pass; Ts=(X@W)*dinv epilogue; gather pure-write.
// R5: bucketed 2-phase CSR build (fill 125us + cnt 65us -> ~60us total).
// R4/R6/R7: forcing W into 64 VGPRs/lane failed (allocator pins VGPR~44-64).
// R8: W in LDS + 4-row unroll -> gemm ~55us (latency-bound on global X
//     row-broadcast loads).
// R9 REGRESSION: 8-row unroll -> VGPR spill (WRITE 207MB scratch).
// R10 REGRESSION: readfirstlane made X rows scalar loads -> SGPR 112, SGPR
//     spill (WRITE 123MB). Lesson: no global row-broadcasts in inner loop.
// R11: fully LDS-resident tiled gemm. Stage W (16KB) + 64-row X tile (16KB,
//     coalesced float4, ReLU fused at staging). Inner loop: only ds_read
//     (W: 2 lanes/bank free; X: same-addr broadcast free) + FMA. 16 accs.
//     32KB LDS -> 5 blocks/CU. No global mem in inner loop at all.
// ---------------------------------------------------------------------------

#define NBK 391          // ceil(100000/256) buckets; arrays padded to 512

// LDS histogram of dst>>8, merged to global.
__global__ void hist_kernel(const int* __restrict__ dst,
                            int* __restrict__ bcnt, int ne) {
    __shared__ int h[512];
    for (int i = threadIdx.x; i < 512; i += blockDim.x) h[i] = 0;
    __syncthreads();
    int stride = gridDim.x * blockDim.x;
    for (int e = blockIdx.x * blockDim.x + threadIdx.x; e < ne; e += stride)
        atomicAdd(&h[dst[e] >> 8], 1);
    __syncthreads();
    for (int i = threadIdx.x; i < 512; i += blockDim.x)
        if (h[i]) atomicAdd(&bcnt[i], h[i]);
}

// One block: exclusive scan of bucket counts -> bbase[0..nb], seed gcur.
__global__ void bscan_kernel(const int* __restrict__ bcnt,
                             int* __restrict__ bbase,
                             int* __restrict__ gcur, int nb, int ne) {
    __shared__ int sh[512];
    int t = threadIdx.x;
    int v = (t < nb) ? bcnt[t] : 0;
    sh[t] = v;
    __syncthreads();
    for (int off = 1; off < 512; off <<= 1) {
        int u = (t >= off) ? sh[t - off] : 0;
        __syncthreads();
        sh[t] += u;
        __syncthreads();
    }
    if (t < nb) {
        int e = sh[t] - v;
        bbase[t] = e;
        gcur[t] = e;
    }
    if (t == 0) bbase[nb] = ne;
}

// Redistribute edges into bucket regions. Per-WG: LDS chunk histogram,
// one global atomic per touched bucket reserves a dense run, LDS cursors
// place edges. packed = {(local8<<24)|src17, w}.
__global__ void scatterB_kernel(const int* __restrict__ src,
                                const int* __restrict__ dst,
                                const float* __restrict__ ew,
                                int* __restrict__ gcur,
                                int2* __restrict__ packed, int ne) {
    __shared__ int h[512];
    __shared__ int cur[512];
    int chunk = (ne + gridDim.x - 1) / gridDim.x;
    int e0 = blockIdx.x * chunk;
    int e1 = e0 + chunk; if (e1 > ne) e1 = ne;
    for (int i = threadIdx.x; i < 512; i += blockDim.x) h[i] = 0;
    __syncthreads();
    for (int e = e0 + threadIdx.x; e < e1; e += blockDim.x)
        atomicAdd(&h[dst[e] >> 8], 1);
    __syncthreads();
    for (int i = threadIdx.x; i < 512; i += blockDim.x)
        cur[i] = h[i] ? atomicAdd(&gcur[i], h[i]) : 0;
    __syncthreads();
    for (int e = e0 + threadIdx.x; e < e1; e += blockDim.x) {
        int d = dst[e];
        int pos = atomicAdd(&cur[d >> 8], 1);   // LDS atomic
        int2 v;
        v.x = ((d & 255) << 24) | src[e];       // src < 2^17, fits
        v.y = __float_as_int(ew[e]);
        packed[pos] = v;
    }
}

// One WG per bucket (256 nodes). Count per node in LDS, LDS scan -> rptr/cnt,
// scatter final CSR within the bucket's own window (L2-hot), then per-thread
// sequential row-sum of w -> dinv. No global atomics anywhere.
__global__ void bucket_build_kernel(const int2* __restrict__ packed,
                                    const int* __restrict__ bbase,
                                    int* __restrict__ rptr,
                                    int* __restrict__ cnt,
                                    float* __restrict__ dinv,
                                    int2* __restrict__ csr, int n) {
    __shared__ int cl[256];
    __shared__ int sc[256];
    __shared__ int cur[256];
    int b = blockIdx.x;
    int t = threadIdx.x;
    int node0 = b << 8;
    int nn = n - node0; if (nn > 256) nn = 256;
    int ebase = bbase[b];
    int m = bbase[b + 1] - ebase;
    cl[t] = 0;
    __syncthreads();
    for (int j = t; j < m; j += 256) {
        int local = ((unsigned)packed[ebase + j].x) >> 24;
        atomicAdd(&cl[local], 1);               // LDS atomic
    }
    __syncthreads();
    int c = cl[t];
    sc[t] = c;
    __syncthreads();
    for (int off = 1; off < 256; off <<= 1) {
        int u = (t >= off) ? sc[t - off] : 0;
        __syncthreads();
        sc[t] += u;
        __syncthreads();
    }
    int base = ebase + sc[t] - c;               // global CSR row start
    cur[t] = base;
    if (t < nn) {
        rptr[node0 + t] = base;
        cnt[node0 + t] = c;
    }
    __syncthreads();
    for (int j = t; j < m; j += 256) {
        int2 p = packed[ebase + j];
        int local = ((unsigned)p.x) >> 24;
        int pos = atomicAdd(&cur[local], 1);    // LDS atomic
        int2 v;
        v.x = p.x & 0x00FFFFFF;
        v.y = p.y;
        csr[pos] = v;
    }
    __syncthreads();
    if (t < nn) {
        float s = 0.0f;
        for (int j = base; j < base + c; ++j)
            s += __int_as_float(csr[j].y);
        dinv[node0 + t] = 1.0f / sqrtf(s + 1.0f);
    }
}

// Fully LDS-resident tiled GEMM. Per block: W (16KB) staged once; per tile
// of 64 rows: X-tile (16KB) staged with coalesced float4 loads, ReLU fused.
// Wave w computes rows w*16..w*16+15, lane = output column, 16 accumulators.
// Inner loop: ds_read only (W b32: 2 lanes/bank = free; X b128 same-addr
// broadcast = free) -- no global memory, no allocator pressure.
template <bool RELU>
__global__ void __launch_bounds__(256, 4)
gemm_tile_kernel(const float* __restrict__ X, const float* __restrict__ W,
                 const float* __restrict__ dinv, float* __restrict__ Ts,
                 int n) {
    __shared__ float Wl[4096];
    __shared__ float Xl[4096];
    {
        const float4* Wv = (const float4*)W;
        float4* Lv = (float4*)Wl;
        for (int i = threadIdx.x; i < 1024; i += 256) Lv[i] = Wv[i];
    }
    int lane = threadIdx.x & 63;
    int w = threadIdx.x >> 6;           // wave 0..3 -> rows w*16..w*16+15
    int ntile = (n + 63) >> 6;
    for (int tile = blockIdx.x; tile < ntile; tile += gridDim.x) {
        int rbase = tile << 6;
        __syncthreads();                // Xl free (also covers W stage, it 0)
        {
            const float4* Xv = (const float4*)(X + (size_t)rbase * 64);
            float4* Lx = (float4*)Xl;
            int maxf = (n - rbase < 64 ? n - rbase : 64) * 16;
            for (int f = threadIdx.x; f < 1024; f += 256) {
                float4 v;
                if (f < maxf) v = Xv[f];
                else { v.x = 0.f; v.y = 0.f; v.z = 0.f; v.w = 0.f; }
                if (RELU) {
                    v.x = fmaxf(v.x, 0.f); v.y = fmaxf(v.y, 0.f);
                    v.z = fmaxf(v.z, 0.f); v.w = fmaxf(v.w, 0.f);
                }
                Lx[f] = v;
            }
        }
        __syncthreads();
        float acc[16];
#pragma unroll
        for (int i = 0; i < 16; ++i) acc[i] = 0.f;
        const float4* Xrow = (const float4*)(Xl + w * 16 * 64);
#pragma unroll
        for (int k4 = 0; k4 < 16; ++k4) {
            float w0 = Wl[(4 * k4 + 0) * 64 + lane];
            float w1 = Wl[(4 * k4 + 1) * 64 + lane];
            float w2 = Wl[(4 * k4 + 2) * 64 + lane];
            float w3 = Wl[(4 * k4 + 3) * 64 + lane];
#pragma unroll
            for (int i = 0; i < 16; ++i) {
                float4 x4 = Xrow[i * 16 + k4];
                acc[i] = fmaf(x4.x, w0, acc[i]);
                acc[i] = fmaf(x4.y, w1, acc[i]);
                acc[i] = fmaf(x4.z, w2, acc[i]);
                acc[i] = fmaf(x4.w, w3, acc[i]);
            }
        }
        int rw = rbase + w * 16;
#pragma unroll
        for (int i = 0; i < 16; ++i) {
            int r = rw + i;
            if (r < n)
                Ts[(size_t)r * 64 + lane] = acc[i] * dinv[r];
        }
    }
}

// One wave per dst row. 4 subgroups of 16 lanes; subgroup handles every 4th
// edge; lane's float4 covers channels 4*cl..4*cl+3. One dwordx4 VMEM instr
// serves 4 edges. A[r] = dinv[r]*(sum + Ts[r]) + b  (pure write).
__global__ void gather_kernel(const int2* __restrict__ csr,
                              const int* __restrict__ rptr,
                              const int* __restrict__ cnt,
                              const float* __restrict__ dinv,
                              const float* __restrict__ b,
                              const float* __restrict__ Ts,
                              float* __restrict__ A, int n) {
    int lane = threadIdx.x & 63;
    int r = (int)(((size_t)blockIdx.x * blockDim.x + threadIdx.x) >> 6);
    if (r >= n) return;
    int sub = lane >> 4;          // 0..3: edge subgroup
    int cl  = lane & 15;          // channel quad
    int start = rptr[r];
    int m = cnt[r];
    float4 a0 = {0.f, 0.f, 0.f, 0.f};
    float4 a1 = {0.f, 0.f, 0.f, 0.f};
    int j = sub;
    for (; j + 4 < m; j += 8) {
        int2 e0 = csr[start + j];
        int2 e1 = csr[start + j + 4];
        float w0 = __int_as_float(e0.y);
        float w1 = __int_as_float(e1.y);
        float4 t0 = *(const float4*)&Ts[(size_t)e0.x * 64 + cl * 4];
        float4 t1 = *(const float4*)&Ts[(size_t)e1.x * 64 + cl * 4];
        a0.x = fmaf(t0.x, w0, a0.x); a0.y = fmaf(t0.y, w0, a0.y);
        a0.z = fmaf(t0.z, w0, a0.z); a0.w = fmaf(t0.w, w0, a0.w);
        a1.x = fmaf(t1.x, w1, a1.x); a1.y = fmaf(t1.y, w1, a1.y);
        a1.z = fmaf(t1.z, w1, a1.z); a1.w = fmaf(t1.w, w1, a1.w);
    }
    if (j < m) {
        int2 e0 = csr[start + j];
        float w0 = __int_as_float(e0.y);
        float4 t0 = *(const float4*)&Ts[(size_t)e0.x * 64 + cl * 4];
        a0.x = fmaf(t0.x, w0, a0.x); a0.y = fmaf(t0.y, w0, a0.y);
        a0.z = fmaf(t0.z, w0, a0.z); a0.w = fmaf(t0.w, w0, a0.w);
    }
    a0.x += a1.x; a0.y += a1.y; a0.z += a1.z; a0.w += a1.w;
#pragma unroll
    for (int off = 16; off < 64; off <<= 1) {
        a0.x += __shfl_xor(a0.x, off);
        a0.y += __shfl_xor(a0.y, off);
        a0.z += __shfl_xor(a0.z, off);
        a0.w += __shfl_xor(a0.w, off);
    }
    if (sub == 0) {
        float dv = dinv[r];
        float4 ts = *(const float4*)&Ts[(size_t)r * 64 + cl * 4];
        float4 bb = *(const float4*)&b[cl * 4];
        float4 o;
        o.x = fmaf(dv, a0.x + ts.x, bb.x);
        o.y = fmaf(dv, a0.y + ts.y, bb.y);
        o.z = fmaf(dv, a0.z + ts.z, bb.z);
        o.w = fmaf(dv, a0.w + ts.w, bb.w);
        *(float4*)&A[(size_t)r * 64 + cl * 4] = o;
    }
}

// Thread per node: sv = relu(h @ Wr0 + br0) @ Wr1 + br1.
// batch is sorted -> wave-segmented suffix reduction, heads do the atomics.
__global__ void readout_kernel(const float* __restrict__ H,
                               const float* __restrict__ Wr0,
                               const float* __restrict__ br0,
                               const float* __restrict__ Wr1,
                               const float* __restrict__ br1,
                               const int* __restrict__ batch,
                               float* __restrict__ gsum,
                               float* __restrict__ gcnt, int n) {
    __shared__ float Ws[64 * 32];
    __shared__ float w1s[32];
    for (int i = threadIdx.x; i < 64 * 32; i += blockDim.x) Ws[i] = Wr0[i];
    if (threadIdx.x < 32) w1s[threadIdx.x] = Wr1[threadIdx.x];
    __syncthreads();
    int r = blockIdx.x * blockDim.x + threadIdx.x;
    int lane = threadIdx.x & 63;
    float sv = 0.0f;
    int g = -1;
    if (r < n) {
        float h[64];
        const float4* hr = (const float4*)(H + (size_t)r * 64);
#pragma unroll
        for (int i = 0; i < 16; ++i) {
            float4 v = hr[i];
            h[4 * i + 0] = v.x; h[4 * i + 1] = v.y;
            h[4 * i + 2] = v.z; h[4 * i + 3] = v.w;
        }
        float ssum = 0.0f;
#pragma unroll 1
        for (int jg = 0; jg < 8; ++jg) {
            float a0 = br0[jg * 4 + 0], a1 = br0[jg * 4 + 1];
            float a2 = br0[jg * 4 + 2], a3 = br0[jg * 4 + 3];
#pragma unroll
            for (int k = 0; k < 64; ++k) {
                const float4 wv = *(const float4*)&Ws[k * 32 + jg * 4];
                a0 = fmaf(h[k], wv.x, a0);
                a1 = fmaf(h[k], wv.y, a1);
                a2 = fmaf(h[k], wv.z, a2);
                a3 = fmaf(h[k], wv.w, a3);
            }
            a0 = fmaxf(a0, 0.0f); a1 = fmaxf(a1, 0.0f);
            a2 = fmaxf(a2, 0.0f); a3 = fmaxf(a3, 0.0f);
            ssum += a0 * w1s[jg * 4 + 0] + a1 * w1s[jg * 4 + 1] +
                    a2 * w1s[jg * 4 + 2] + a3 * w1s[jg * 4 + 3];
        }
        sv = ssum + br1[0];
        g = batch[r];
    }
    float c = (r < n) ? 1.0f : 0.0f;
#pragma unroll
    for (int off = 1; off < 64; off <<= 1) {
        int   og = __shfl_down(g, off);
        float ov = __shfl_down(sv, off);
        float oc = __shfl_down(c, off);
        if ((lane + off) < 64 && og == g) { sv += ov; c += oc; }
    }
    int gprev = __shfl_up(g, 1);
    bool head = (lane == 0) || (gprev != g);
    if (head && g >= 0) {
        atomicAdd(&gsum[g], sv);
        atomicAdd(&gcnt[g], c);
    }
}

__global__ void pool_fin_kernel(const float* __restrict__ gsum,
                                const float* __restrict__ gcnt,
                                float* __restrict__ out, int ng) {
    int g = blockIdx.x * blockDim.x + threadIdx.x;
    if (g < ng) out[g] = gsum[g] / fmaxf(gcnt[g], 1.0f);
}

extern "C" void kernel_launch(void* const* d_in, const int* in_sizes, int n_in,
                              void* d_out, int out_size, void* d_ws, size_t ws_size,
                              hipStream_t stream) {
    const float* x    = (const float*)d_in[0];
    const int*   ei   = (const int*)d_in[1];
    const float* ew   = (const float*)d_in[2];
    const int*   batch= (const int*)d_in[3];
    const float* W0   = (const float*)d_in[4];
    const float* b0   = (const float*)d_in[5];
    const float* W1   = (const float*)d_in[6];
    const float* b1   = (const float*)d_in[7];
    const float* W2   = (const float*)d_in[8];
    const float* b2   = (const float*)d_in[9];
    const float* Wr0  = (const float*)d_in[10];
    const float* br0  = (const float*)d_in[11];
    const float* Wr1  = (const float*)d_in[12];
    const float* br1  = (const float*)d_in[13];
    float* out = (float*)d_out;

    int n  = in_sizes[0] / 64;   // 100000
    int ne = in_sizes[1] / 2;    // 1600000
    int ng = out_size;           // 256
    const int* srcv = ei;
    const int* dstv = ei + ne;
    int nbk = (n + 255) >> 8;    // 391

    char* ws = (char*)d_ws;
    size_t off = 0;
    auto alloc = [&](size_t bytes) {
        void* p = ws + off;
        off += (bytes + 255) & ~(size_t)255;
        return p;
    };
    float* Ts     = (float*)alloc((size_t)n * 64 * sizeof(float));
    float* A      = (float*)alloc((size_t)n * 64 * sizeof(float));
    float* dinv   = (float*)alloc((size_t)n * sizeof(float));
    int*   cnt    = (int*)alloc((size_t)n * sizeof(int));
    int*   rptr   = (int*)alloc((size_t)n * sizeof(int));
    int*   bcnt   = (int*)alloc(520 * sizeof(int));
    int*   bbase  = (int*)alloc(520 * sizeof(int));
    int*   gcur   = (int*)alloc(520 * sizeof(int));
    int2*  csr    = (int2*)alloc((size_t)ne * sizeof(int2));
    float* gsum   = (float*)alloc((size_t)ng * sizeof(float));
    float* gcnt   = (float*)alloc((size_t)ng * sizeof(float));
    // packed aliases Ts: consumed by bucket_build before first gemm writes Ts.
    int2*  packed = (int2*)Ts;
    (void)ws_size;

    hipMemsetAsync(bcnt, 0, 520 * sizeof(int), stream);
    hipMemsetAsync(gsum, 0, (size_t)ng * sizeof(float), stream);
    hipMemsetAsync(gcnt, 0, (size_t)ng * sizeof(float), stream);

    hist_kernel<<<256, 256, 0, stream>>>(dstv, bcnt, ne);
    bscan_kernel<<<1, 512, 0, stream>>>(bcnt, bbase, gcur, nbk, ne);
    scatterB_kernel<<<200, 256, 0, stream>>>(srcv, dstv, ew, gcur, packed, ne);
    bucket_build_kernel<<<nbk, 256, 0, stream>>>(packed, bbase, rptr, cnt,
                                                 dinv, csr, n);

    const int gemm_blocks = 1280;   // 5 blocks/CU at 32KB LDS
    unsigned gat_blocks = (unsigned)(((size_t)n * 64 + 255) / 256);

    gemm_tile_kernel<false><<<gemm_blocks, 256, 0, stream>>>(x, W0, dinv, Ts, n);
    gather_kernel<<<gat_blocks, 256, 0, stream>>>(csr, rptr, cnt, dinv, b0, Ts, A, n);

    gemm_tile_kernel<true><<<gemm_blocks, 256, 0, stream>>>(A, W1, dinv, Ts, n);
    gather_kernel<<<gat_blocks, 256, 0, stream>>>(csr, rptr, cnt, dinv, b1, Ts, A, n);

    gemm_tile_kernel<true><<<gemm_blocks, 256, 0, stream>>>(A, W2, dinv, Ts, n);
    gather_kernel<<<gat_blocks, 256, 0, stream>>>(csr, rptr, cnt, dinv, b2, Ts, A, n);

    readout_kernel<<<(n + 255) / 256, 256, 0, stream>>>(A, Wr0, br0, Wr1, br1,
                                                        batch, gsum, gcnt, n);
    pool_fin_kernel<<<(ng + 255) / 256, 256, 0, stream>>>(gsum, gcnt, out, ng);
}

// Round 12
// 449.478 us; speedup vs baseline: 5.5503x; 5.5503x over previous
//
#include <hip/hip_runtime.h>

// ---------------------------------------------------------------------------
// Petri_GCN: 3x GCNConv(64->64) + MLP readout (64->32->1) + segment-mean pool
// All fp32 (abs threshold forbids bf16/MFMA; no fp32 MFMA on CDNA4).
// R1: CSR-by-dst + gather instead of atomic scatter.
// R2: readout wave-segmented atomics; gather 4x(16-lane x float4) layout.
// R3: count-only atomic pass; Ts=(X@W)*dinv epilogue; gather pure-write.
// R5: bucketed 2-phase CSR build (fill 125us + cnt 65us -> ~60us total).
// R4/R6/R7: forcing W into 64 VGPRs/lane failed (allocator pins VGPR~44-64).
// R8: W in LDS + 4-row unroll -> gemm ~55us (BEST KNOWN GEMM; latency-bound,
//     occupancy grid-capped at 1024 blocks = 16 waves/CU = 50%).
// R9/R10/R11 ALL REGRESSED (spill cliffs): 8-row unroll (WRITE 207MB),
//     readfirstlane scalar X loads (SGPR 112, WRITE 123MB), LDS-tile 16-acc
//     full unroll (WRITE 1.5GB!). Lesson: R8's 4-row shape is at the edge of
//     the VGPR budget; ANY added in-flight state spills. Scratch = WRITE_SIZE.
// R12: exact R8 kernels; ONE change: gemm grid 1024 -> 2048 (8 blocks/CU,
//     128KB LDS of 160, doubles latency hiding). Single-variable test.
// ---------------------------------------------------------------------------

#define NBK 391          // ceil(100000/256) buckets; arrays padded to 512

// LDS histogram of dst>>8, merged to global.
__global__ void hist_kernel(const int* __restrict__ dst,
                            int* __restrict__ bcnt, int ne) {
    __shared__ int h[512];
    for (int i = threadIdx.x; i < 512; i += blockDim.x) h[i] = 0;
    __syncthreads();
    int stride = gridDim.x * blockDim.x;
    for (int e = blockIdx.x * blockDim.x + threadIdx.x; e < ne; e += stride)
        atomicAdd(&h[dst[e] >> 8], 1);
    __syncthreads();
    for (int i = threadIdx.x; i < 512; i += blockDim.x)
        if (h[i]) atomicAdd(&bcnt[i], h[i]);
}

// One block: exclusive scan of bucket counts -> bbase[0..nb], seed gcur.
__global__ void bscan_kernel(const int* __restrict__ bcnt,
                             int* __restrict__ bbase,
                             int* __restrict__ gcur, int nb, int ne) {
    __shared__ int sh[512];
    int t = threadIdx.x;
    int v = (t < nb) ? bcnt[t] : 0;
    sh[t] = v;
    __syncthreads();
    for (int off = 1; off < 512; off <<= 1) {
        int u = (t >= off) ? sh[t - off] : 0;
        __syncthreads();
        sh[t] += u;
        __syncthreads();
    }
    if (t < nb) {
        int e = sh[t] - v;
        bbase[t] = e;
        gcur[t] = e;
    }
    if (t == 0) bbase[nb] = ne;
}

// Redistribute edges into bucket regions. Per-WG: LDS chunk histogram,
// one global atomic per touched bucket reserves a dense run, LDS cursors
// place edges. packed = {(local8<<24)|src17, w}.
__global__ void scatterB_kernel(const int* __restrict__ src,
                                const int* __restrict__ dst,
                                const float* __restrict__ ew,
                                int* __restrict__ gcur,
                                int2* __restrict__ packed, int ne) {
    __shared__ int h[512];
    __shared__ int cur[512];
    int chunk = (ne + gridDim.x - 1) / gridDim.x;
    int e0 = blockIdx.x * chunk;
    int e1 = e0 + chunk; if (e1 > ne) e1 = ne;
    for (int i = threadIdx.x; i < 512; i += blockDim.x) h[i] = 0;
    __syncthreads();
    for (int e = e0 + threadIdx.x; e < e1; e += blockDim.x)
        atomicAdd(&h[dst[e] >> 8], 1);
    __syncthreads();
    for (int i = threadIdx.x; i < 512; i += blockDim.x)
        cur[i] = h[i] ? atomicAdd(&gcur[i], h[i]) : 0;
    __syncthreads();
    for (int e = e0 + threadIdx.x; e < e1; e += blockDim.x) {
        int d = dst[e];
        int pos = atomicAdd(&cur[d >> 8], 1);   // LDS atomic
        int2 v;
        v.x = ((d & 255) << 24) | src[e];       // src < 2^17, fits
        v.y = __float_as_int(ew[e]);
        packed[pos] = v;
    }
}

// One WG per bucket (256 nodes). Count per node in LDS, LDS scan -> rptr/cnt,
// scatter final CSR within the bucket's own window (L2-hot), then per-thread
// sequential row-sum of w -> dinv. No global atomics anywhere.
__global__ void bucket_build_kernel(const int2* __restrict__ packed,
                                    const int* __restrict__ bbase,
                                    int* __restrict__ rptr,
                                    int* __restrict__ cnt,
                                    float* __restrict__ dinv,
                                    int2* __restrict__ csr, int n) {
    __shared__ int cl[256];
    __shared__ int sc[256];
    __shared__ int cur[256];
    int b = blockIdx.x;
    int t = threadIdx.x;
    int node0 = b << 8;
    int nn = n - node0; if (nn > 256) nn = 256;
    int ebase = bbase[b];
    int m = bbase[b + 1] - ebase;
    cl[t] = 0;
    __syncthreads();
    for (int j = t; j < m; j += 256) {
        int local = ((unsigned)packed[ebase + j].x) >> 24;
        atomicAdd(&cl[local], 1);               // LDS atomic
    }
    __syncthreads();
    int c = cl[t];
    sc[t] = c;
    __syncthreads();
    for (int off = 1; off < 256; off <<= 1) {
        int u = (t >= off) ? sc[t - off] : 0;
        __syncthreads();
        sc[t] += u;
        __syncthreads();
    }
    int base = ebase + sc[t] - c;               // global CSR row start
    cur[t] = base;
    if (t < nn) {
        rptr[node0 + t] = base;
        cnt[node0 + t] = c;
    }
    __syncthreads();
    for (int j = t; j < m; j += 256) {
        int2 p = packed[ebase + j];
        int local = ((unsigned)p.x) >> 24;
        int pos = atomicAdd(&cur[local], 1);    // LDS atomic
        int2 v;
        v.x = p.x & 0x00FFFFFF;
        v.y = p.y;
        csr[pos] = v;
    }
    __syncthreads();
    if (t < nn) {
        float s = 0.0f;
        for (int j = base; j < base + c; ++j)
            s += __int_as_float(csr[j].y);
        dinv[node0 + t] = 1.0f / sqrtf(s + 1.0f);
    }
}

// GEMM (exact R8 shape -- the only non-spilling variant): W staged in LDS
// (16KB); each wave processes 4 rows per iteration. Lane = output column.
// W ds_read amortized over 4 rows; X rows via uniform float4 broadcasts.
// Ts = act(X)@W * dinv[r].
template <bool RELU>
__global__ void __launch_bounds__(256, 4)
gemm_lds_kernel(const float* X, const float* W,
                const float* __restrict__ dinv, float* Ts, int n) {
    __shared__ float Wl[4096];
    {
        const float4* Wv = (const float4*)W;
        float4* Lv = (float4*)Wl;
        for (int i = threadIdx.x; i < 1024; i += 256) Lv[i] = Wv[i];
    }
    __syncthreads();
    int lane = threadIdx.x & 63;
    int wid  = (blockIdx.x * blockDim.x + threadIdx.x) >> 6;
    int nw   = (gridDim.x * blockDim.x) >> 6;
    for (int r0 = wid * 4; r0 < n; r0 += nw * 4) {
        if (r0 + 4 <= n) {
            const float4* x0 = (const float4*)(X + (size_t)(r0 + 0) * 64);
            const float4* x1 = (const float4*)(X + (size_t)(r0 + 1) * 64);
            const float4* x2 = (const float4*)(X + (size_t)(r0 + 2) * 64);
            const float4* x3 = (const float4*)(X + (size_t)(r0 + 3) * 64);
            float acc0 = 0.f, acc1 = 0.f, acc2 = 0.f, acc3 = 0.f;
#pragma unroll
            for (int k4 = 0; k4 < 16; ++k4) {
                float4 a0 = x0[k4], a1 = x1[k4], a2 = x2[k4], a3 = x3[k4];
                if (RELU) {
                    a0.x = fmaxf(a0.x, 0.f); a0.y = fmaxf(a0.y, 0.f);
                    a0.z = fmaxf(a0.z, 0.f); a0.w = fmaxf(a0.w, 0.f);
                    a1.x = fmaxf(a1.x, 0.f); a1.y = fmaxf(a1.y, 0.f);
                    a1.z = fmaxf(a1.z, 0.f); a1.w = fmaxf(a1.w, 0.f);
                    a2.x = fmaxf(a2.x, 0.f); a2.y = fmaxf(a2.y, 0.f);
                    a2.z = fmaxf(a2.z, 0.f); a2.w = fmaxf(a2.w, 0.f);
                    a3.x = fmaxf(a3.x, 0.f); a3.y = fmaxf(a3.y, 0.f);
                    a3.z = fmaxf(a3.z, 0.f); a3.w = fmaxf(a3.w, 0.f);
                }
                float w0 = Wl[(4 * k4 + 0) * 64 + lane];
                float w1 = Wl[(4 * k4 + 1) * 64 + lane];
                float w2 = Wl[(4 * k4 + 2) * 64 + lane];
                float w3 = Wl[(4 * k4 + 3) * 64 + lane];
                acc0 = fmaf(a0.x, w0, acc0); acc0 = fmaf(a0.y, w1, acc0);
                acc0 = fmaf(a0.z, w2, acc0); acc0 = fmaf(a0.w, w3, acc0);
                acc1 = fmaf(a1.x, w0, acc1); acc1 = fmaf(a1.y, w1, acc1);
                acc1 = fmaf(a1.z, w2, acc1); acc1 = fmaf(a1.w, w3, acc1);
                acc2 = fmaf(a2.x, w0, acc2); acc2 = fmaf(a2.y, w1, acc2);
                acc2 = fmaf(a2.z, w2, acc2); acc2 = fmaf(a2.w, w3, acc2);
                acc3 = fmaf(a3.x, w0, acc3); acc3 = fmaf(a3.y, w1, acc3);
                acc3 = fmaf(a3.z, w2, acc3); acc3 = fmaf(a3.w, w3, acc3);
            }
            Ts[(size_t)(r0 + 0) * 64 + lane] = acc0 * dinv[r0 + 0];
            Ts[(size_t)(r0 + 1) * 64 + lane] = acc1 * dinv[r0 + 1];
            Ts[(size_t)(r0 + 2) * 64 + lane] = acc2 * dinv[r0 + 2];
            Ts[(size_t)(r0 + 3) * 64 + lane] = acc3 * dinv[r0 + 3];
        } else {
            for (int r = r0; r < n; ++r) {
                const float4* xr = (const float4*)(X + (size_t)r * 64);
                float acc = 0.f;
#pragma unroll
                for (int k4 = 0; k4 < 16; ++k4) {
                    float4 a = xr[k4];
                    if (RELU) {
                        a.x = fmaxf(a.x, 0.f); a.y = fmaxf(a.y, 0.f);
                        a.z = fmaxf(a.z, 0.f); a.w = fmaxf(a.w, 0.f);
                    }
                    acc = fmaf(a.x, Wl[(4 * k4 + 0) * 64 + lane], acc);
                    acc = fmaf(a.y, Wl[(4 * k4 + 1) * 64 + lane], acc);
                    acc = fmaf(a.z, Wl[(4 * k4 + 2) * 64 + lane], acc);
                    acc = fmaf(a.w, Wl[(4 * k4 + 3) * 64 + lane], acc);
                }
                Ts[(size_t)r * 64 + lane] = acc * dinv[r];
            }
        }
    }
}

// One wave per dst row. 4 subgroups of 16 lanes; subgroup handles every 4th
// edge; lane's float4 covers channels 4*cl..4*cl+3. One dwordx4 VMEM instr
// serves 4 edges. A[r] = dinv[r]*(sum + Ts[r]) + b  (pure write).
__global__ void gather_kernel(const int2* __restrict__ csr,
                              const int* __restrict__ rptr,
                              const int* __restrict__ cnt,
                              const float* __restrict__ dinv,
                              const float* __restrict__ b,
                              const float* __restrict__ Ts,
                              float* __restrict__ A, int n) {
    int lane = threadIdx.x & 63;
    int r = (int)(((size_t)blockIdx.x * blockDim.x + threadIdx.x) >> 6);
    if (r >= n) return;
    int sub = lane >> 4;          // 0..3: edge subgroup
    int cl  = lane & 15;          // channel quad
    int start = rptr[r];
    int m = cnt[r];
    float4 a0 = {0.f, 0.f, 0.f, 0.f};
    float4 a1 = {0.f, 0.f, 0.f, 0.f};
    int j = sub;
    for (; j + 4 < m; j += 8) {
        int2 e0 = csr[start + j];
        int2 e1 = csr[start + j + 4];
        float w0 = __int_as_float(e0.y);
        float w1 = __int_as_float(e1.y);
        float4 t0 = *(const float4*)&Ts[(size_t)e0.x * 64 + cl * 4];
        float4 t1 = *(const float4*)&Ts[(size_t)e1.x * 64 + cl * 4];
        a0.x = fmaf(t0.x, w0, a0.x); a0.y = fmaf(t0.y, w0, a0.y);
        a0.z = fmaf(t0.z, w0, a0.z); a0.w = fmaf(t0.w, w0, a0.w);
        a1.x = fmaf(t1.x, w1, a1.x); a1.y = fmaf(t1.y, w1, a1.y);
        a1.z = fmaf(t1.z, w1, a1.z); a1.w = fmaf(t1.w, w1, a1.w);
    }
    if (j < m) {
        int2 e0 = csr[start + j];
        float w0 = __int_as_float(e0.y);
        float4 t0 = *(const float4*)&Ts[(size_t)e0.x * 64 + cl * 4];
        a0.x = fmaf(t0.x, w0, a0.x); a0.y = fmaf(t0.y, w0, a0.y);
        a0.z = fmaf(t0.z, w0, a0.z); a0.w = fmaf(t0.w, w0, a0.w);
    }
    a0.x += a1.x; a0.y += a1.y; a0.z += a1.z; a0.w += a1.w;
#pragma unroll
    for (int off = 16; off < 64; off <<= 1) {
        a0.x += __shfl_xor(a0.x, off);
        a0.y += __shfl_xor(a0.y, off);
        a0.z += __shfl_xor(a0.z, off);
        a0.w += __shfl_xor(a0.w, off);
    }
    if (sub == 0) {
        float dv = dinv[r];
        float4 ts = *(const float4*)&Ts[(size_t)r * 64 + cl * 4];
        float4 bb = *(const float4*)&b[cl * 4];
        float4 o;
        o.x = fmaf(dv, a0.x + ts.x, bb.x);
        o.y = fmaf(dv, a0.y + ts.y, bb.y);
        o.z = fmaf(dv, a0.z + ts.z, bb.z);
        o.w = fmaf(dv, a0.w + ts.w, bb.w);
        *(float4*)&A[(size_t)r * 64 + cl * 4] = o;
    }
}

// Thread per node: sv = relu(h @ Wr0 + br0) @ Wr1 + br1.
// batch is sorted -> wave-segmented suffix reduction, heads do the atomics.
__global__ void readout_kernel(const float* __restrict__ H,
                               const float* __restrict__ Wr0,
                               const float* __restrict__ br0,
                               const float* __restrict__ Wr1,
                               const float* __restrict__ br1,
                               const int* __restrict__ batch,
                               float* __restrict__ gsum,
                               float* __restrict__ gcnt, int n) {
    __shared__ float Ws[64 * 32];
    __shared__ float w1s[32];
    for (int i = threadIdx.x; i < 64 * 32; i += blockDim.x) Ws[i] = Wr0[i];
    if (threadIdx.x < 32) w1s[threadIdx.x] = Wr1[threadIdx.x];
    __syncthreads();
    int r = blockIdx.x * blockDim.x + threadIdx.x;
    int lane = threadIdx.x & 63;
    float sv = 0.0f;
    int g = -1;
    if (r < n) {
        float h[64];
        const float4* hr = (const float4*)(H + (size_t)r * 64);
#pragma unroll
        for (int i = 0; i < 16; ++i) {
            float4 v = hr[i];
            h[4 * i + 0] = v.x; h[4 * i + 1] = v.y;
            h[4 * i + 2] = v.z; h[4 * i + 3] = v.w;
        }
        float ssum = 0.0f;
#pragma unroll 1
        for (int jg = 0; jg < 8; ++jg) {
            float a0 = br0[jg * 4 + 0], a1 = br0[jg * 4 + 1];
            float a2 = br0[jg * 4 + 2], a3 = br0[jg * 4 + 3];
#pragma unroll
            for (int k = 0; k < 64; ++k) {
                const float4 wv = *(const float4*)&Ws[k * 32 + jg * 4];
                a0 = fmaf(h[k], wv.x, a0);
                a1 = fmaf(h[k], wv.y, a1);
                a2 = fmaf(h[k], wv.z, a2);
                a3 = fmaf(h[k], wv.w, a3);
            }
            a0 = fmaxf(a0, 0.0f); a1 = fmaxf(a1, 0.0f);
            a2 = fmaxf(a2, 0.0f); a3 = fmaxf(a3, 0.0f);
            ssum += a0 * w1s[jg * 4 + 0] + a1 * w1s[jg * 4 + 1] +
                    a2 * w1s[jg * 4 + 2] + a3 * w1s[jg * 4 + 3];
        }
        sv = ssum + br1[0];
        g = batch[r];
    }
    float c = (r < n) ? 1.0f : 0.0f;
#pragma unroll
    for (int off = 1; off < 64; off <<= 1) {
        int   og = __shfl_down(g, off);
        float ov = __shfl_down(sv, off);
        float oc = __shfl_down(c, off);
        if ((lane + off) < 64 && og == g) { sv += ov; c += oc; }
    }
    int gprev = __shfl_up(g, 1);
    bool head = (lane == 0) || (gprev != g);
    if (head && g >= 0) {
        atomicAdd(&gsum[g], sv);
        atomicAdd(&gcnt[g], c);
    }
}

__global__ void pool_fin_kernel(const float* __restrict__ gsum,
                                const float* __restrict__ gcnt,
                                float* __restrict__ out, int ng) {
    int g = blockIdx.x * blockDim.x + threadIdx.x;
    if (g < ng) out[g] = gsum[g] / fmaxf(gcnt[g], 1.0f);
}

extern "C" void kernel_launch(void* const* d_in, const int* in_sizes, int n_in,
                              void* d_out, int out_size, void* d_ws, size_t ws_size,
                              hipStream_t stream) {
    const float* x    = (const float*)d_in[0];
    const int*   ei   = (const int*)d_in[1];
    const float* ew   = (const float*)d_in[2];
    const int*   batch= (const int*)d_in[3];
    const float* W0   = (const float*)d_in[4];
    const float* b0   = (const float*)d_in[5];
    const float* W1   = (const float*)d_in[6];
    const float* b1   = (const float*)d_in[7];
    const float* W2   = (const float*)d_in[8];
    const float* b2   = (const float*)d_in[9];
    const float* Wr0  = (const float*)d_in[10];
    const float* br0  = (const float*)d_in[11];
    const float* Wr1  = (const float*)d_in[12];
    const float* br1  = (const float*)d_in[13];
    float* out = (float*)d_out;

    int n  = in_sizes[0] / 64;   // 100000
    int ne = in_sizes[1] / 2;    // 1600000
    int ng = out_size;           // 256
    const int* srcv = ei;
    const int* dstv = ei + ne;
    int nbk = (n + 255) >> 8;    // 391

    char* ws = (char*)d_ws;
    size_t off = 0;
    auto alloc = [&](size_t bytes) {
        void* p = ws + off;
        off += (bytes + 255) & ~(size_t)255;
        return p;
    };
    float* Ts     = (float*)alloc((size_t)n * 64 * sizeof(float));
    float* A      = (float*)alloc((size_t)n * 64 * sizeof(float));
    float* dinv   = (float*)alloc((size_t)n * sizeof(float));
    int*   cnt    = (int*)alloc((size_t)n * sizeof(int));
    int*   rptr   = (int*)alloc((size_t)n * sizeof(int));
    int*   bcnt   = (int*)alloc(520 * sizeof(int));
    int*   bbase  = (int*)alloc(520 * sizeof(int));
    int*   gcur   = (int*)alloc(520 * sizeof(int));
    int2*  csr    = (int2*)alloc((size_t)ne * sizeof(int2));
    float* gsum   = (float*)alloc((size_t)ng * sizeof(float));
    float* gcnt   = (float*)alloc((size_t)ng * sizeof(float));
    // packed aliases Ts: consumed by bucket_build before first gemm writes Ts.
    int2*  packed = (int2*)Ts;
    (void)ws_size;

    hipMemsetAsync(bcnt, 0, 520 * sizeof(int), stream);
    hipMemsetAsync(gsum, 0, (size_t)ng * sizeof(float), stream);
    hipMemsetAsync(gcnt, 0, (size_t)ng * sizeof(float), stream);

    hist_kernel<<<256, 256, 0, stream>>>(dstv, bcnt, ne);
    bscan_kernel<<<1, 512, 0, stream>>>(bcnt, bbase, gcur, nbk, ne);
    scatterB_kernel<<<200, 256, 0, stream>>>(srcv, dstv, ew, gcur, packed, ne);
    bucket_build_kernel<<<nbk, 256, 0, stream>>>(packed, bbase, rptr, cnt,
                                                 dinv, csr, n);

    const int gemm_blocks = 2048;   // R12: only change vs R8 (was 1024)
    unsigned gat_blocks = (unsigned)(((size_t)n * 64 + 255) / 256);

    gemm_lds_kernel<false><<<gemm_blocks, 256, 0, stream>>>(x, W0, dinv, Ts, n);
    gather_kernel<<<gat_blocks, 256, 0, stream>>>(csr, rptr, cnt, dinv, b0, Ts, A, n);

    gemm_lds_kernel<true><<<gemm_blocks, 256, 0, stream>>>(A, W1, dinv, Ts, n);
    gather_kernel<<<gat_blocks, 256, 0, stream>>>(csr, rptr, cnt, dinv, b1, Ts, A, n);

    gemm_lds_kernel<true><<<gemm_blocks, 256, 0, stream>>>(A, W2, dinv, Ts, n);
    gather_kernel<<<gat_blocks, 256, 0, stream>>>(csr, rptr, cnt, dinv, b2, Ts, A, n);

    readout_kernel<<<(n + 255) / 256, 256, 0, stream>>>(A, Wr0, br0, Wr1, br1,
                                                        batch, gsum, gcnt, n);
    pool_fin_kernel<<<(ng + 255) / 256, 256, 0, stream>>>(gsum, gcnt, out, ng);
}

// Round 13
// 385.805 us; speedup vs baseline: 6.4663x; 1.1650x over previous
//
#include <hip/hip_runtime.h>

// ---------------------------------------------------------------------------
// Petri_GCN: 3x GCNConv(64->64) + MLP readout (64->32->1) + segment-mean pool
// All fp32 (abs threshold forbids bf16/MFMA; no fp32 MFMA on CDNA4).
// R1: CSR-by-dst + gather instead of atomic scatter.
// R2: readout wave-segmented atomics; gather 4x(16-lane x float4) layout.
// R3: count-only atomic pass; Ts=(X@W)*dinv epilogue; gather pure-write.
// R5: bucketed 2-phase CSR build (fill 125us + cnt 65us -> ~60us total).
// R4/R6/R7: forcing W into 64 VGPRs/lane failed (allocator pins VGPR~44-64).
// R8/R12: W in LDS + 4-row unroll, grid 2048 -> gemm ~55-65us. Limiter:
//     64 uniform-broadcast global X loads per tile, ~300cyc each, ILP~4.
// R9/R10/R11 REGRESSIONS (spill cliffs from many in-flight loads / scalar-
//     load SGPR pressure / 16-acc LDS tile). Scratch = WRITE_SIZE blowup.
// R13: gemm_rl: ONE coalesced dwordx4 loads the whole 4-row X tile (lane l ->
//     row l>>4, chans 4(l&15)); broadcasts via v_readlane (const lane idx
//     after unroll) feed FMAs as the SGPR operand. Per tile: 1 VMEM + 64
//     ds_read_b32 (W) + 256 readlane + 256 FMA; ReLU 256->4 ops. No in-
//     flight load state -> no spill surface. gather: 4-stream unroll (ILP 2->4).
// ---------------------------------------------------------------------------

#define NBK 391          // ceil(100000/256) buckets; arrays padded to 512

__device__ __forceinline__ float bcastf(float v, int l) {
    return __int_as_float(__builtin_amdgcn_readlane(__float_as_int(v), l));
}

// LDS histogram of dst>>8, merged to global.
__global__ void hist_kernel(const int* __restrict__ dst,
                            int* __restrict__ bcnt, int ne) {
    __shared__ int h[512];
    for (int i = threadIdx.x; i < 512; i += blockDim.x) h[i] = 0;
    __syncthreads();
    int stride = gridDim.x * blockDim.x;
    for (int e = blockIdx.x * blockDim.x + threadIdx.x; e < ne; e += stride)
        atomicAdd(&h[dst[e] >> 8], 1);
    __syncthreads();
    for (int i = threadIdx.x; i < 512; i += blockDim.x)
        if (h[i]) atomicAdd(&bcnt[i], h[i]);
}

// One block: exclusive scan of bucket counts -> bbase[0..nb], seed gcur.
__global__ void bscan_kernel(const int* __restrict__ bcnt,
                             int* __restrict__ bbase,
                             int* __restrict__ gcur, int nb, int ne) {
    __shared__ int sh[512];
    int t = threadIdx.x;
    int v = (t < nb) ? bcnt[t] : 0;
    sh[t] = v;
    __syncthreads();
    for (int off = 1; off < 512; off <<= 1) {
        int u = (t >= off) ? sh[t - off] : 0;
        __syncthreads();
        sh[t] += u;
        __syncthreads();
    }
    if (t < nb) {
        int e = sh[t] - v;
        bbase[t] = e;
        gcur[t] = e;
    }
    if (t == 0) bbase[nb] = ne;
}

// Redistribute edges into bucket regions. Per-WG: LDS chunk histogram,
// one global atomic per touched bucket reserves a dense run, LDS cursors
// place edges. packed = {(local8<<24)|src17, w}.
__global__ void scatterB_kernel(const int* __restrict__ src,
                                const int* __restrict__ dst,
                                const float* __restrict__ ew,
                                int* __restrict__ gcur,
                                int2* __restrict__ packed, int ne) {
    __shared__ int h[512];
    __shared__ int cur[512];
    int chunk = (ne + gridDim.x - 1) / gridDim.x;
    int e0 = blockIdx.x * chunk;
    int e1 = e0 + chunk; if (e1 > ne) e1 = ne;
    for (int i = threadIdx.x; i < 512; i += blockDim.x) h[i] = 0;
    __syncthreads();
    for (int e = e0 + threadIdx.x; e < e1; e += blockDim.x)
        atomicAdd(&h[dst[e] >> 8], 1);
    __syncthreads();
    for (int i = threadIdx.x; i < 512; i += blockDim.x)
        cur[i] = h[i] ? atomicAdd(&gcur[i], h[i]) : 0;
    __syncthreads();
    for (int e = e0 + threadIdx.x; e < e1; e += blockDim.x) {
        int d = dst[e];
        int pos = atomicAdd(&cur[d >> 8], 1);   // LDS atomic
        int2 v;
        v.x = ((d & 255) << 24) | src[e];       // src < 2^17, fits
        v.y = __float_as_int(ew[e]);
        packed[pos] = v;
    }
}

// One WG per bucket (256 nodes). Count per node in LDS, LDS scan -> rptr/cnt,
// scatter final CSR within the bucket's own window (L2-hot), then per-thread
// sequential row-sum of w -> dinv. No global atomics anywhere.
__global__ void bucket_build_kernel(const int2* __restrict__ packed,
                                    const int* __restrict__ bbase,
                                    int* __restrict__ rptr,
                                    int* __restrict__ cnt,
                                    float* __restrict__ dinv,
                                    int2* __restrict__ csr, int n) {
    __shared__ int cl[256];
    __shared__ int sc[256];
    __shared__ int cur[256];
    int b = blockIdx.x;
    int t = threadIdx.x;
    int node0 = b << 8;
    int nn = n - node0; if (nn > 256) nn = 256;
    int ebase = bbase[b];
    int m = bbase[b + 1] - ebase;
    cl[t] = 0;
    __syncthreads();
    for (int j = t; j < m; j += 256) {
        int local = ((unsigned)packed[ebase + j].x) >> 24;
        atomicAdd(&cl[local], 1);               // LDS atomic
    }
    __syncthreads();
    int c = cl[t];
    sc[t] = c;
    __syncthreads();
    for (int off = 1; off < 256; off <<= 1) {
        int u = (t >= off) ? sc[t - off] : 0;
        __syncthreads();
        sc[t] += u;
        __syncthreads();
    }
    int base = ebase + sc[t] - c;               // global CSR row start
    cur[t] = base;
    if (t < nn) {
        rptr[node0 + t] = base;
        cnt[node0 + t] = c;
    }
    __syncthreads();
    for (int j = t; j < m; j += 256) {
        int2 p = packed[ebase + j];
        int local = ((unsigned)p.x) >> 24;
        int pos = atomicAdd(&cur[local], 1);    // LDS atomic
        int2 v;
        v.x = p.x & 0x00FFFFFF;
        v.y = p.y;
        csr[pos] = v;
    }
    __syncthreads();
    if (t < nn) {
        float s = 0.0f;
        for (int j = base; j < base + c; ++j)
            s += __int_as_float(csr[j].y);
        dinv[node0 + t] = 1.0f / sqrtf(s + 1.0f);
    }
}

// GEMM via readlane broadcast: one coalesced dwordx4 per wave loads the
// whole 4-row X tile (lane l -> row r0+(l>>4), channels 4*(l&15)..+3).
// The FMA operand "X[row][4k4+c]" is lane (row*16+k4)'s component c ->
// v_readlane with compile-time lane index -> SGPR operand of v_fmac.
// W staged in LDS, read b32 per k (2 lanes/bank = conflict-free).
// Ts = act(X)@W * dinv[r]. Minimal live state: no spill surface.
template <bool RELU>
__global__ void __launch_bounds__(256, 4)
gemm_rl_kernel(const float* __restrict__ X, const float* W,
               const float* __restrict__ dinv, float* __restrict__ Ts,
               int n) {
    __shared__ float Wl[4096];
    {
        const float4* Wv = (const float4*)W;
        float4* Lv = (float4*)Wl;
        for (int i = threadIdx.x; i < 1024; i += 256) Lv[i] = Wv[i];
    }
    __syncthreads();
    int lane = threadIdx.x & 63;
    int wid  = (blockIdx.x * blockDim.x + threadIdx.x) >> 6;
    int nw   = (gridDim.x * blockDim.x) >> 6;
    int lrow = lane >> 4;          // row this lane loads
    int lcol = (lane & 15) * 4;    // channel quad this lane loads
    for (int r0 = wid * 4; r0 + 4 <= n; r0 += nw * 4) {
        float4 xv = *(const float4*)&X[(size_t)(r0 + lrow) * 64 + lcol];
        if (RELU) {
            xv.x = fmaxf(xv.x, 0.f); xv.y = fmaxf(xv.y, 0.f);
            xv.z = fmaxf(xv.z, 0.f); xv.w = fmaxf(xv.w, 0.f);
        }
        float a0 = 0.f, a1 = 0.f, a2 = 0.f, a3 = 0.f;
#pragma unroll
        for (int k4 = 0; k4 < 16; ++k4) {
            float w0 = Wl[(4 * k4 + 0) * 64 + lane];
            float w1 = Wl[(4 * k4 + 1) * 64 + lane];
            float w2 = Wl[(4 * k4 + 2) * 64 + lane];
            float w3 = Wl[(4 * k4 + 3) * 64 + lane];
            a0 = fmaf(bcastf(xv.x, k4), w0, a0);
            a0 = fmaf(bcastf(xv.y, k4), w1, a0);
            a0 = fmaf(bcastf(xv.z, k4), w2, a0);
            a0 = fmaf(bcastf(xv.w, k4), w3, a0);
            a1 = fmaf(bcastf(xv.x, 16 + k4), w0, a1);
            a1 = fmaf(bcastf(xv.y, 16 + k4), w1, a1);
            a1 = fmaf(bcastf(xv.z, 16 + k4), w2, a1);
            a1 = fmaf(bcastf(xv.w, 16 + k4), w3, a1);
            a2 = fmaf(bcastf(xv.x, 32 + k4), w0, a2);
            a2 = fmaf(bcastf(xv.y, 32 + k4), w1, a2);
            a2 = fmaf(bcastf(xv.z, 32 + k4), w2, a2);
            a2 = fmaf(bcastf(xv.w, 32 + k4), w3, a2);
            a3 = fmaf(bcastf(xv.x, 48 + k4), w0, a3);
            a3 = fmaf(bcastf(xv.y, 48 + k4), w1, a3);
            a3 = fmaf(bcastf(xv.z, 48 + k4), w2, a3);
            a3 = fmaf(bcastf(xv.w, 48 + k4), w3, a3);
        }
        Ts[(size_t)(r0 + 0) * 64 + lane] = a0 * dinv[r0 + 0];
        Ts[(size_t)(r0 + 1) * 64 + lane] = a1 * dinv[r0 + 1];
        Ts[(size_t)(r0 + 2) * 64 + lane] = a2 * dinv[r0 + 2];
        Ts[(size_t)(r0 + 3) * 64 + lane] = a3 * dinv[r0 + 3];
    }
    // tail rows (n % 4 != 0): one wave handles them (cold: n=100000)
    if (wid == 0) {
        for (int r = (n & ~3); r < n; ++r) {
            const float4* xr = (const float4*)(X + (size_t)r * 64);
            float acc = 0.f;
#pragma unroll
            for (int k4 = 0; k4 < 16; ++k4) {
                float4 a = xr[k4];
                if (RELU) {
                    a.x = fmaxf(a.x, 0.f); a.y = fmaxf(a.y, 0.f);
                    a.z = fmaxf(a.z, 0.f); a.w = fmaxf(a.w, 0.f);
                }
                acc = fmaf(a.x, Wl[(4 * k4 + 0) * 64 + lane], acc);
                acc = fmaf(a.y, Wl[(4 * k4 + 1) * 64 + lane], acc);
                acc = fmaf(a.z, Wl[(4 * k4 + 2) * 64 + lane], acc);
                acc = fmaf(a.w, Wl[(4 * k4 + 3) * 64 + lane], acc);
            }
            Ts[(size_t)r * 64 + lane] = acc * dinv[r];
        }
    }
}

// One wave per dst row. 4 subgroups of 16 lanes; subgroup handles every 4th
// edge; lane's float4 covers channels 4*cl..4*cl+3. R13: 4 edge streams in
// flight per subgroup (ILP 4). A[r] = dinv[r]*(sum + Ts[r]) + b (pure write).
__global__ void gather_kernel(const int2* __restrict__ csr,
                              const int* __restrict__ rptr,
                              const int* __restrict__ cnt,
                              const float* __restrict__ dinv,
                              const float* __restrict__ b,
                              const float* __restrict__ Ts,
                              float* __restrict__ A, int n) {
    int lane = threadIdx.x & 63;
    int r = (int)(((size_t)blockIdx.x * blockDim.x + threadIdx.x) >> 6);
    if (r >= n) return;
    int sub = lane >> 4;          // 0..3: edge subgroup
    int cl  = lane & 15;          // channel quad
    int start = rptr[r];
    int m = cnt[r];
    float4 a0 = {0.f, 0.f, 0.f, 0.f};
    float4 a1 = {0.f, 0.f, 0.f, 0.f};
    float4 a2 = {0.f, 0.f, 0.f, 0.f};
    float4 a3 = {0.f, 0.f, 0.f, 0.f};
    int j = sub;
    for (; j + 12 < m; j += 16) {
        int2 e0 = csr[start + j];
        int2 e1 = csr[start + j + 4];
        int2 e2 = csr[start + j + 8];
        int2 e3 = csr[start + j + 12];
        float w0 = __int_as_float(e0.y);
        float w1 = __int_as_float(e1.y);
        float w2 = __int_as_float(e2.y);
        float w3 = __int_as_float(e3.y);
        float4 t0 = *(const float4*)&Ts[(size_t)e0.x * 64 + cl * 4];
        float4 t1 = *(const float4*)&Ts[(size_t)e1.x * 64 + cl * 4];
        float4 t2 = *(const float4*)&Ts[(size_t)e2.x * 64 + cl * 4];
        float4 t3 = *(const float4*)&Ts[(size_t)e3.x * 64 + cl * 4];
        a0.x = fmaf(t0.x, w0, a0.x); a0.y = fmaf(t0.y, w0, a0.y);
        a0.z = fmaf(t0.z, w0, a0.z); a0.w = fmaf(t0.w, w0, a0.w);
        a1.x = fmaf(t1.x, w1, a1.x); a1.y = fmaf(t1.y, w1, a1.y);
        a1.z = fmaf(t1.z, w1, a1.z); a1.w = fmaf(t1.w, w1, a1.w);
        a2.x = fmaf(t2.x, w2, a2.x); a2.y = fmaf(t2.y, w2, a2.y);
        a2.z = fmaf(t2.z, w2, a2.z); a2.w = fmaf(t2.w, w2, a2.w);
        a3.x = fmaf(t3.x, w3, a3.x); a3.y = fmaf(t3.y, w3, a3.y);
        a3.z = fmaf(t3.z, w3, a3.z); a3.w = fmaf(t3.w, w3, a3.w);
    }
    for (; j < m; j += 4) {
        int2 e0 = csr[start + j];
        float w0 = __int_as_float(e0.y);
        float4 t0 = *(const float4*)&Ts[(size_t)e0.x * 64 + cl * 4];
        a0.x = fmaf(t0.x, w0, a0.x); a0.y = fmaf(t0.y, w0, a0.y);
        a0.z = fmaf(t0.z, w0, a0.z); a0.w = fmaf(t0.w, w0, a0.w);
    }
    a0.x += a1.x + a2.x + a3.x;
    a0.y += a1.y + a2.y + a3.y;
    a0.z += a1.z + a2.z + a3.z;
    a0.w += a1.w + a2.w + a3.w;
#pragma unroll
    for (int off = 16; off < 64; off <<= 1) {
        a0.x += __shfl_xor(a0.x, off);
        a0.y += __shfl_xor(a0.y, off);
        a0.z += __shfl_xor(a0.z, off);
        a0.w += __shfl_xor(a0.w, off);
    }
    if (sub == 0) {
        float dv = dinv[r];
        float4 ts = *(const float4*)&Ts[(size_t)r * 64 + cl * 4];
        float4 bb = *(const float4*)&b[cl * 4];
        float4 o;
        o.x = fmaf(dv, a0.x + ts.x, bb.x);
        o.y = fmaf(dv, a0.y + ts.y, bb.y);
        o.z = fmaf(dv, a0.z + ts.z, bb.z);
        o.w = fmaf(dv, a0.w + ts.w, bb.w);
        *(float4*)&A[(size_t)r * 64 + cl * 4] = o;
    }
}

// Thread per node: sv = relu(h @ Wr0 + br0) @ Wr1 + br1.
// batch is sorted -> wave-segmented suffix reduction, heads do the atomics.
__global__ void readout_kernel(const float* __restrict__ H,
                               const float* __restrict__ Wr0,
                               const float* __restrict__ br0,
                               const float* __restrict__ Wr1,
                               const float* __restrict__ br1,
                               const int* __restrict__ batch,
                               float* __restrict__ gsum,
                               float* __restrict__ gcnt, int n) {
    __shared__ float Ws[64 * 32];
    __shared__ float w1s[32];
    for (int i = threadIdx.x; i < 64 * 32; i += blockDim.x) Ws[i] = Wr0[i];
    if (threadIdx.x < 32) w1s[threadIdx.x] = Wr1[threadIdx.x];
    __syncthreads();
    int r = blockIdx.x * blockDim.x + threadIdx.x;
    int lane = threadIdx.x & 63;
    float sv = 0.0f;
    int g = -1;
    if (r < n) {
        float h[64];
        const float4* hr = (const float4*)(H + (size_t)r * 64);
#pragma unroll
        for (int i = 0; i < 16; ++i) {
            float4 v = hr[i];
            h[4 * i + 0] = v.x; h[4 * i + 1] = v.y;
            h[4 * i + 2] = v.z; h[4 * i + 3] = v.w;
        }
        float ssum = 0.0f;
#pragma unroll 1
        for (int jg = 0; jg < 8; ++jg) {
            float a0 = br0[jg * 4 + 0], a1 = br0[jg * 4 + 1];
            float a2 = br0[jg * 4 + 2], a3 = br0[jg * 4 + 3];
#pragma unroll
            for (int k = 0; k < 64; ++k) {
                const float4 wv = *(const float4*)&Ws[k * 32 + jg * 4];
                a0 = fmaf(h[k], wv.x, a0);
                a1 = fmaf(h[k], wv.y, a1);
                a2 = fmaf(h[k], wv.z, a2);
                a3 = fmaf(h[k], wv.w, a3);
            }
            a0 = fmaxf(a0, 0.0f); a1 = fmaxf(a1, 0.0f);
            a2 = fmaxf(a2, 0.0f); a3 = fmaxf(a3, 0.0f);
            ssum += a0 * w1s[jg * 4 + 0] + a1 * w1s[jg * 4 + 1] +
                    a2 * w1s[jg * 4 + 2] + a3 * w1s[jg * 4 + 3];
        }
        sv = ssum + br1[0];
        g = batch[r];
    }
    float c = (r < n) ? 1.0f : 0.0f;
#pragma unroll
    for (int off = 1; off < 64; off <<= 1) {
        int   og = __shfl_down(g, off);
        float ov = __shfl_down(sv, off);
        float oc = __shfl_down(c, off);
        if ((lane + off) < 64 && og == g) { sv += ov; c += oc; }
    }
    int gprev = __shfl_up(g, 1);
    bool head = (lane == 0) || (gprev != g);
    if (head && g >= 0) {
        atomicAdd(&gsum[g], sv);
        atomicAdd(&gcnt[g], c);
    }
}

__global__ void pool_fin_kernel(const float* __restrict__ gsum,
                                const float* __restrict__ gcnt,
                                float* __restrict__ out, int ng) {
    int g = blockIdx.x * blockDim.x + threadIdx.x;
    if (g < ng) out[g] = gsum[g] / fmaxf(gcnt[g], 1.0f);
}

extern "C" void kernel_launch(void* const* d_in, const int* in_sizes, int n_in,
                              void* d_out, int out_size, void* d_ws, size_t ws_size,
                              hipStream_t stream) {
    const float* x    = (const float*)d_in[0];
    const int*   ei   = (const int*)d_in[1];
    const float* ew   = (const float*)d_in[2];
    const int*   batch= (const int*)d_in[3];
    const float* W0   = (const float*)d_in[4];
    const float* b0   = (const float*)d_in[5];
    const float* W1   = (const float*)d_in[6];
    const float* b1   = (const float*)d_in[7];
    const float* W2   = (const float*)d_in[8];
    const float* b2   = (const float*)d_in[9];
    const float* Wr0  = (const float*)d_in[10];
    const float* br0  = (const float*)d_in[11];
    const float* Wr1  = (const float*)d_in[12];
    const float* br1  = (const float*)d_in[13];
    float* out = (float*)d_out;

    int n  = in_sizes[0] / 64;   // 100000
    int ne = in_sizes[1] / 2;    // 1600000
    int ng = out_size;           // 256
    const int* srcv = ei;
    const int* dstv = ei + ne;
    int nbk = (n + 255) >> 8;    // 391

    char* ws = (char*)d_ws;
    size_t off = 0;
    auto alloc = [&](size_t bytes) {
        void* p = ws + off;
        off += (bytes + 255) & ~(size_t)255;
        return p;
    };
    float* Ts     = (float*)alloc((size_t)n * 64 * sizeof(float));
    float* A      = (float*)alloc((size_t)n * 64 * sizeof(float));
    float* dinv   = (float*)alloc((size_t)n * sizeof(float));
    int*   cnt    = (int*)alloc((size_t)n * sizeof(int));
    int*   rptr   = (int*)alloc((size_t)n * sizeof(int));
    int*   bcnt   = (int*)alloc(520 * sizeof(int));
    int*   bbase  = (int*)alloc(520 * sizeof(int));
    int*   gcur   = (int*)alloc(520 * sizeof(int));
    int2*  csr    = (int2*)alloc((size_t)ne * sizeof(int2));
    float* gsum   = (float*)alloc((size_t)ng * sizeof(float));
    float* gcnt   = (float*)alloc((size_t)ng * sizeof(float));
    // packed aliases Ts: consumed by bucket_build before first gemm writes Ts.
    int2*  packed = (int2*)Ts;
    (void)ws_size;

    hipMemsetAsync(bcnt, 0, 520 * sizeof(int), stream);
    hipMemsetAsync(gsum, 0, (size_t)ng * sizeof(float), stream);
    hipMemsetAsync(gcnt, 0, (size_t)ng * sizeof(float), stream);

    hist_kernel<<<256, 256, 0, stream>>>(dstv, bcnt, ne);
    bscan_kernel<<<1, 512, 0, stream>>>(bcnt, bbase, gcur, nbk, ne);
    scatterB_kernel<<<200, 256, 0, stream>>>(srcv, dstv, ew, gcur, packed, ne);
    bucket_build_kernel<<<nbk, 256, 0, stream>>>(packed, bbase, rptr, cnt,
                                                 dinv, csr, n);

    const int gemm_blocks = 2048;
    unsigned gat_blocks = (unsigned)(((size_t)n * 64 + 255) / 256);

    gemm_rl_kernel<false><<<gemm_blocks, 256, 0, stream>>>(x, W0, dinv, Ts, n);
    gather_kernel<<<gat_blocks, 256, 0, stream>>>(csr, rptr, cnt, dinv, b0, Ts, A, n);

    gemm_rl_kernel<true><<<gemm_blocks, 256, 0, stream>>>(A, W1, dinv, Ts, n);
    gather_kernel<<<gat_blocks, 256, 0, stream>>>(csr, rptr, cnt, dinv, b1, Ts, A, n);

    gemm_rl_kernel<true><<<gemm_blocks, 256, 0, stream>>>(A, W2, dinv, Ts, n);
    gather_kernel<<<gat_blocks, 256, 0, stream>>>(csr, rptr, cnt, dinv, b2, Ts, A, n);

    readout_kernel<<<(n + 255) / 256, 256, 0, stream>>>(A, Wr0, br0, Wr1, br1,
                                                        batch, gsum, gcnt, n);
    pool_fin_kernel<<<(ng + 255) / 256, 256, 0, stream>>>(gsum, gcnt, out, ng);
}

// Round 14
// 359.701 us; speedup vs baseline: 6.9356x; 1.0726x over previous
//
#include <hip/hip_runtime.h>

// ---------------------------------------------------------------------------
// Petri_GCN: 3x GCNConv(64->64) + MLP readout (64->32->1) + segment-mean pool
// All fp32 (abs threshold forbids bf16/MFMA; no fp32 MFMA on CDNA4).
// R1: CSR-by-dst + gather instead of atomic scatter.
// R2: readout wave-segmented atomics; gather 4x(16-lane x float4) layout.
// R3: count-only atomic pass; Ts=(X@W)*dinv epilogue; gather pure-write.
// R5: bucketed 2-phase CSR build.
// R8/R12: W in LDS gemm (no spill shape). R9/R10/R11: spill cliffs (lesson:
//     scratch traffic = WRITE_SIZE blowup; avoid many in-flight loads).
// R13: gemm_rl readlane-broadcast gemm (1 coalesced VMEM/tile) -> gemm ~35us.
//     gather 4-stream unroll NEUTRAL -> gather is L2-miss-BW-bound, VALU 31%.
// R14: FUSE gemm into gather epilogue (layers 1,2). Butterfly reduce leaves
//     full sum in ALL lanes -> every lane holds its 4 chans of A[r]; relu;
//     64 readlane broadcasts + 64 FMA + LDS W reads compute Ts_next[r]
//     under the memory-bound gather (69% VALU headroom). A1/A2 never
//     materialized (-38MB traffic/layer); 2 gemm dispatches deleted.
// ---------------------------------------------------------------------------

#define NBK 391          // ceil(100000/256) buckets; arrays padded to 512

__device__ __forceinline__ float bcastf(float v, int l) {
    return __int_as_float(__builtin_amdgcn_readlane(__float_as_int(v), l));
}

// LDS histogram of dst>>8, merged to global.
__global__ void hist_kernel(const int* __restrict__ dst,
                            int* __restrict__ bcnt, int ne) {
    __shared__ int h[512];
    for (int i = threadIdx.x; i < 512; i += blockDim.x) h[i] = 0;
    __syncthreads();
    int stride = gridDim.x * blockDim.x;
    for (int e = blockIdx.x * blockDim.x + threadIdx.x; e < ne; e += stride)
        atomicAdd(&h[dst[e] >> 8], 1);
    __syncthreads();
    for (int i = threadIdx.x; i < 512; i += blockDim.x)
        if (h[i]) atomicAdd(&bcnt[i], h[i]);
}

// One block: exclusive scan of bucket counts -> bbase[0..nb], seed gcur.
__global__ void bscan_kernel(const int* __restrict__ bcnt,
                             int* __restrict__ bbase,
                             int* __restrict__ gcur, int nb, int ne) {
    __shared__ int sh[512];
    int t = threadIdx.x;
    int v = (t < nb) ? bcnt[t] : 0;
    sh[t] = v;
    __syncthreads();
    for (int off = 1; off < 512; off <<= 1) {
        int u = (t >= off) ? sh[t - off] : 0;
        __syncthreads();
        sh[t] += u;
        __syncthreads();
    }
    if (t < nb) {
        int e = sh[t] - v;
        bbase[t] = e;
        gcur[t] = e;
    }
    if (t == 0) bbase[nb] = ne;
}

// Redistribute edges into bucket regions. Per-WG: LDS chunk histogram,
// one global atomic per touched bucket reserves a dense run, LDS cursors
// place edges. packed = {(local8<<24)|src17, w}.
__global__ void scatterB_kernel(const int* __restrict__ src,
                                const int* __restrict__ dst,
                                const float* __restrict__ ew,
                                int* __restrict__ gcur,
                                int2* __restrict__ packed, int ne) {
    __shared__ int h[512];
    __shared__ int cur[512];
    int chunk = (ne + gridDim.x - 1) / gridDim.x;
    int e0 = blockIdx.x * chunk;
    int e1 = e0 + chunk; if (e1 > ne) e1 = ne;
    for (int i = threadIdx.x; i < 512; i += blockDim.x) h[i] = 0;
    __syncthreads();
    for (int e = e0 + threadIdx.x; e < e1; e += blockDim.x)
        atomicAdd(&h[dst[e] >> 8], 1);
    __syncthreads();
    for (int i = threadIdx.x; i < 512; i += blockDim.x)
        cur[i] = h[i] ? atomicAdd(&gcur[i], h[i]) : 0;
    __syncthreads();
    for (int e = e0 + threadIdx.x; e < e1; e += blockDim.x) {
        int d = dst[e];
        int pos = atomicAdd(&cur[d >> 8], 1);   // LDS atomic
        int2 v;
        v.x = ((d & 255) << 24) | src[e];       // src < 2^17, fits
        v.y = __float_as_int(ew[e]);
        packed[pos] = v;
    }
}

// One WG per bucket (256 nodes). Count per node in LDS, LDS scan -> rptr/cnt,
// scatter final CSR within the bucket's own window (L2-hot), then per-thread
// sequential row-sum of w -> dinv. No global atomics anywhere.
__global__ void bucket_build_kernel(const int2* __restrict__ packed,
                                    const int* __restrict__ bbase,
                                    int* __restrict__ rptr,
                                    int* __restrict__ cnt,
                                    float* __restrict__ dinv,
                                    int2* __restrict__ csr, int n) {
    __shared__ int cl[256];
    __shared__ int sc[256];
    __shared__ int cur[256];
    int b = blockIdx.x;
    int t = threadIdx.x;
    int node0 = b << 8;
    int nn = n - node0; if (nn > 256) nn = 256;
    int ebase = bbase[b];
    int m = bbase[b + 1] - ebase;
    cl[t] = 0;
    __syncthreads();
    for (int j = t; j < m; j += 256) {
        int local = ((unsigned)packed[ebase + j].x) >> 24;
        atomicAdd(&cl[local], 1);               // LDS atomic
    }
    __syncthreads();
    int c = cl[t];
    sc[t] = c;
    __syncthreads();
    for (int off = 1; off < 256; off <<= 1) {
        int u = (t >= off) ? sc[t - off] : 0;
        __syncthreads();
        sc[t] += u;
        __syncthreads();
    }
    int base = ebase + sc[t] - c;               // global CSR row start
    cur[t] = base;
    if (t < nn) {
        rptr[node0 + t] = base;
        cnt[node0 + t] = c;
    }
    __syncthreads();
    for (int j = t; j < m; j += 256) {
        int2 p = packed[ebase + j];
        int local = ((unsigned)p.x) >> 24;
        int pos = atomicAdd(&cur[local], 1);    // LDS atomic
        int2 v;
        v.x = p.x & 0x00FFFFFF;
        v.y = p.y;
        csr[pos] = v;
    }
    __syncthreads();
    if (t < nn) {
        float s = 0.0f;
        for (int j = base; j < base + c; ++j)
            s += __int_as_float(csr[j].y);
        dinv[node0 + t] = 1.0f / sqrtf(s + 1.0f);
    }
}

// GEMM via readlane broadcast (R13, proven): one coalesced dwordx4 per wave
// loads the whole 4-row X tile; broadcasts via v_readlane feed FMAs.
template <bool RELU>
__global__ void __launch_bounds__(256, 4)
gemm_rl_kernel(const float* __restrict__ X, const float* W,
               const float* __restrict__ dinv, float* __restrict__ Ts,
               int n) {
    __shared__ float Wl[4096];
    {
        const float4* Wv = (const float4*)W;
        float4* Lv = (float4*)Wl;
        for (int i = threadIdx.x; i < 1024; i += 256) Lv[i] = Wv[i];
    }
    __syncthreads();
    int lane = threadIdx.x & 63;
    int wid  = (blockIdx.x * blockDim.x + threadIdx.x) >> 6;
    int nw   = (gridDim.x * blockDim.x) >> 6;
    int lrow = lane >> 4;          // row this lane loads
    int lcol = (lane & 15) * 4;    // channel quad this lane loads
    for (int r0 = wid * 4; r0 + 4 <= n; r0 += nw * 4) {
        float4 xv = *(const float4*)&X[(size_t)(r0 + lrow) * 64 + lcol];
        if (RELU) {
            xv.x = fmaxf(xv.x, 0.f); xv.y = fmaxf(xv.y, 0.f);
            xv.z = fmaxf(xv.z, 0.f); xv.w = fmaxf(xv.w, 0.f);
        }
        float a0 = 0.f, a1 = 0.f, a2 = 0.f, a3 = 0.f;
#pragma unroll
        for (int k4 = 0; k4 < 16; ++k4) {
            float w0 = Wl[(4 * k4 + 0) * 64 + lane];
            float w1 = Wl[(4 * k4 + 1) * 64 + lane];
            float w2 = Wl[(4 * k4 + 2) * 64 + lane];
            float w3 = Wl[(4 * k4 + 3) * 64 + lane];
            a0 = fmaf(bcastf(xv.x, k4), w0, a0);
            a0 = fmaf(bcastf(xv.y, k4), w1, a0);
            a0 = fmaf(bcastf(xv.z, k4), w2, a0);
            a0 = fmaf(bcastf(xv.w, k4), w3, a0);
            a1 = fmaf(bcastf(xv.x, 16 + k4), w0, a1);
            a1 = fmaf(bcastf(xv.y, 16 + k4), w1, a1);
            a1 = fmaf(bcastf(xv.z, 16 + k4), w2, a1);
            a1 = fmaf(bcastf(xv.w, 16 + k4), w3, a1);
            a2 = fmaf(bcastf(xv.x, 32 + k4), w0, a2);
            a2 = fmaf(bcastf(xv.y, 32 + k4), w1, a2);
            a2 = fmaf(bcastf(xv.z, 32 + k4), w2, a2);
            a2 = fmaf(bcastf(xv.w, 32 + k4), w3, a2);
            a3 = fmaf(bcastf(xv.x, 48 + k4), w0, a3);
            a3 = fmaf(bcastf(xv.y, 48 + k4), w1, a3);
            a3 = fmaf(bcastf(xv.z, 48 + k4), w2, a3);
            a3 = fmaf(bcastf(xv.w, 48 + k4), w3, a3);
        }
        Ts[(size_t)(r0 + 0) * 64 + lane] = a0 * dinv[r0 + 0];
        Ts[(size_t)(r0 + 1) * 64 + lane] = a1 * dinv[r0 + 1];
        Ts[(size_t)(r0 + 2) * 64 + lane] = a2 * dinv[r0 + 2];
        Ts[(size_t)(r0 + 3) * 64 + lane] = a3 * dinv[r0 + 3];
    }
    if (wid == 0) {
        for (int r = (n & ~3); r < n; ++r) {
            const float4* xr = (const float4*)(X + (size_t)r * 64);
            float acc = 0.f;
#pragma unroll
            for (int k4 = 0; k4 < 16; ++k4) {
                float4 a = xr[k4];
                if (RELU) {
                    a.x = fmaxf(a.x, 0.f); a.y = fmaxf(a.y, 0.f);
                    a.z = fmaxf(a.z, 0.f); a.w = fmaxf(a.w, 0.f);
                }
                acc = fmaf(a.x, Wl[(4 * k4 + 0) * 64 + lane], acc);
                acc = fmaf(a.y, Wl[(4 * k4 + 1) * 64 + lane], acc);
                acc = fmaf(a.z, Wl[(4 * k4 + 2) * 64 + lane], acc);
                acc = fmaf(a.w, Wl[(4 * k4 + 3) * 64 + lane], acc);
            }
            Ts[(size_t)r * 64 + lane] = acc * dinv[r];
        }
    }
}

// Fused gather + next-layer gemm. Gather as in R13 (4 subgroups x float4,
// 4 edge streams). Butterfly reduce leaves FULL row sum in all 64 lanes ->
// every lane computes its 4 channels of A[r] = dinv*(sum+Ts_self)+b, relu,
// then lane c computes Ts_out[r][c] = dinv[r] * sum_k t_k * Wn[k][c] via
// readlane broadcasts (t_k lives in lane k>>4... lane k/4's component k&3)
// + LDS-staged Wn reads. A row never touches memory.
__global__ void __launch_bounds__(256, 4)
fgather_kernel(const int2* __restrict__ csr,
               const int* __restrict__ rptr,
               const int* __restrict__ cnt,
               const float* __restrict__ dinv,
               const float* __restrict__ b,
               const float* __restrict__ Ts_in,
               const float* Wn,
               float* __restrict__ Ts_out, int n) {
    __shared__ float Wl[4096];
    {
        const float4* Wv = (const float4*)Wn;
        float4* Lv = (float4*)Wl;
        for (int i = threadIdx.x; i < 1024; i += 256) Lv[i] = Wv[i];
    }
    __syncthreads();
    int lane = threadIdx.x & 63;
    int r = (int)(((size_t)blockIdx.x * blockDim.x + threadIdx.x) >> 6);
    if (r >= n) return;   // after the only barrier: safe
    int sub = lane >> 4;
    int cl  = lane & 15;
    int start = rptr[r];
    int m = cnt[r];
    float4 a0 = {0.f, 0.f, 0.f, 0.f};
    float4 a1 = {0.f, 0.f, 0.f, 0.f};
    float4 a2 = {0.f, 0.f, 0.f, 0.f};
    float4 a3 = {0.f, 0.f, 0.f, 0.f};
    int j = sub;
    for (; j + 12 < m; j += 16) {
        int2 e0 = csr[start + j];
        int2 e1 = csr[start + j + 4];
        int2 e2 = csr[start + j + 8];
        int2 e3 = csr[start + j + 12];
        float w0 = __int_as_float(e0.y);
        float w1 = __int_as_float(e1.y);
        float w2 = __int_as_float(e2.y);
        float w3 = __int_as_float(e3.y);
        float4 t0 = *(const float4*)&Ts_in[(size_t)e0.x * 64 + cl * 4];
        float4 t1 = *(const float4*)&Ts_in[(size_t)e1.x * 64 + cl * 4];
        float4 t2 = *(const float4*)&Ts_in[(size_t)e2.x * 64 + cl * 4];
        float4 t3 = *(const float4*)&Ts_in[(size_t)e3.x * 64 + cl * 4];
        a0.x = fmaf(t0.x, w0, a0.x); a0.y = fmaf(t0.y, w0, a0.y);
        a0.z = fmaf(t0.z, w0, a0.z); a0.w = fmaf(t0.w, w0, a0.w);
        a1.x = fmaf(t1.x, w1, a1.x); a1.y = fmaf(t1.y, w1, a1.y);
        a1.z = fmaf(t1.z, w1, a1.z); a1.w = fmaf(t1.w, w1, a1.w);
        a2.x = fmaf(t2.x, w2, a2.x); a2.y = fmaf(t2.y, w2, a2.y);
        a2.z = fmaf(t2.z, w2, a2.z); a2.w = fmaf(t2.w, w2, a2.w);
        a3.x = fmaf(t3.x, w3, a3.x); a3.y = fmaf(t3.y, w3, a3.y);
        a3.z = fmaf(t3.z, w3, a3.z); a3.w = fmaf(t3.w, w3, a3.w);
    }
    for (; j < m; j += 4) {
        int2 e0 = csr[start + j];
        float w0 = __int_as_float(e0.y);
        float4 t0 = *(const float4*)&Ts_in[(size_t)e0.x * 64 + cl * 4];
        a0.x = fmaf(t0.x, w0, a0.x); a0.y = fmaf(t0.y, w0, a0.y);
        a0.z = fmaf(t0.z, w0, a0.z); a0.w = fmaf(t0.w, w0, a0.w);
    }
    a0.x += a1.x + a2.x + a3.x;
    a0.y += a1.y + a2.y + a3.y;
    a0.z += a1.z + a2.z + a3.z;
    a0.w += a1.w + a2.w + a3.w;
#pragma unroll
    for (int off = 16; off < 64; off <<= 1) {
        a0.x += __shfl_xor(a0.x, off);
        a0.y += __shfl_xor(a0.y, off);
        a0.z += __shfl_xor(a0.z, off);
        a0.w += __shfl_xor(a0.w, off);
    }
    // all lanes now hold the full sums for their channel quad (cl)
    float dv = dinv[r];
    float4 ts = *(const float4*)&Ts_in[(size_t)r * 64 + cl * 4];
    float4 bb = *(const float4*)&b[cl * 4];
    float tx = fmaxf(fmaf(dv, a0.x + ts.x, bb.x), 0.f);
    float ty = fmaxf(fmaf(dv, a0.y + ts.y, bb.y), 0.f);
    float tz = fmaxf(fmaf(dv, a0.z + ts.z, bb.z), 0.f);
    float tw = fmaxf(fmaf(dv, a0.w + ts.w, bb.w), 0.f);
    // fused gemm: lane computes output channel `lane`; t_k = comp k&3 of lane k>>2
    float acc = 0.f;
#pragma unroll
    for (int q = 0; q < 16; ++q) {
        acc = fmaf(bcastf(tx, q), Wl[(4 * q + 0) * 64 + lane], acc);
        acc = fmaf(bcastf(ty, q), Wl[(4 * q + 1) * 64 + lane], acc);
        acc = fmaf(bcastf(tz, q), Wl[(4 * q + 2) * 64 + lane], acc);
        acc = fmaf(bcastf(tw, q), Wl[(4 * q + 3) * 64 + lane], acc);
    }
    Ts_out[(size_t)r * 64 + lane] = acc * dv;
}

// Plain gather (final layer): writes A = dinv*(sum+Ts_self)+b.
__global__ void gather_kernel(const int2* __restrict__ csr,
                              const int* __restrict__ rptr,
                              const int* __restrict__ cnt,
                              const float* __restrict__ dinv,
                              const float* __restrict__ b,
                              const float* __restrict__ Ts,
                              float* __restrict__ A, int n) {
    int lane = threadIdx.x & 63;
    int r = (int)(((size_t)blockIdx.x * blockDim.x + threadIdx.x) >> 6);
    if (r >= n) return;
    int sub = lane >> 4;
    int cl  = lane & 15;
    int start = rptr[r];
    int m = cnt[r];
    float4 a0 = {0.f, 0.f, 0.f, 0.f};
    float4 a1 = {0.f, 0.f, 0.f, 0.f};
    float4 a2 = {0.f, 0.f, 0.f, 0.f};
    float4 a3 = {0.f, 0.f, 0.f, 0.f};
    int j = sub;
    for (; j + 12 < m; j += 16) {
        int2 e0 = csr[start + j];
        int2 e1 = csr[start + j + 4];
        int2 e2 = csr[start + j + 8];
        int2 e3 = csr[start + j + 12];
        float w0 = __int_as_float(e0.y);
        float w1 = __int_as_float(e1.y);
        float w2 = __int_as_float(e2.y);
        float w3 = __int_as_float(e3.y);
        float4 t0 = *(const float4*)&Ts[(size_t)e0.x * 64 + cl * 4];
        float4 t1 = *(const float4*)&Ts[(size_t)e1.x * 64 + cl * 4];
        float4 t2 = *(const float4*)&Ts[(size_t)e2.x * 64 + cl * 4];
        float4 t3 = *(const float4*)&Ts[(size_t)e3.x * 64 + cl * 4];
        a0.x = fmaf(t0.x, w0, a0.x); a0.y = fmaf(t0.y, w0, a0.y);
        a0.z = fmaf(t0.z, w0, a0.z); a0.w = fmaf(t0.w, w0, a0.w);
        a1.x = fmaf(t1.x, w1, a1.x); a1.y = fmaf(t1.y, w1, a1.y);
        a1.z = fmaf(t1.z, w1, a1.z); a1.w = fmaf(t1.w, w1, a1.w);
        a2.x = fmaf(t2.x, w2, a2.x); a2.y = fmaf(t2.y, w2, a2.y);
        a2.z = fmaf(t2.z, w2, a2.z); a2.w = fmaf(t2.w, w2, a2.w);
        a3.x = fmaf(t3.x, w3, a3.x); a3.y = fmaf(t3.y, w3, a3.y);
        a3.z = fmaf(t3.z, w3, a3.z); a3.w = fmaf(t3.w, w3, a3.w);
    }
    for (; j < m; j += 4) {
        int2 e0 = csr[start + j];
        float w0 = __int_as_float(e0.y);
        float4 t0 = *(const float4*)&Ts[(size_t)e0.x * 64 + cl * 4];
        a0.x = fmaf(t0.x, w0, a0.x); a0.y = fmaf(t0.y, w0, a0.y);
        a0.z = fmaf(t0.z, w0, a0.z); a0.w = fmaf(t0.w, w0, a0.w);
    }
    a0.x += a1.x + a2.x + a3.x;
    a0.y += a1.y + a2.y + a3.y;
    a0.z += a1.z + a2.z + a3.z;
    a0.w += a1.w + a2.w + a3.w;
#pragma unroll
    for (int off = 16; off < 64; off <<= 1) {
        a0.x += __shfl_xor(a0.x, off);
        a0.y += __shfl_xor(a0.y, off);
        a0.z += __shfl_xor(a0.z, off);
        a0.w += __shfl_xor(a0.w, off);
    }
    if (sub == 0) {
        float dv = dinv[r];
        float4 ts = *(const float4*)&Ts[(size_t)r * 64 + cl * 4];
        float4 bb = *(const float4*)&b[cl * 4];
        float4 o;
        o.x = fmaf(dv, a0.x + ts.x, bb.x);
        o.y = fmaf(dv, a0.y + ts.y, bb.y);
        o.z = fmaf(dv, a0.z + ts.z, bb.z);
        o.w = fmaf(dv, a0.w + ts.w, bb.w);
        *(float4*)&A[(size_t)r * 64 + cl * 4] = o;
    }
}

// Thread per node: sv = relu(h @ Wr0 + br0) @ Wr1 + br1.
// batch is sorted -> wave-segmented suffix reduction, heads do the atomics.
__global__ void readout_kernel(const float* __restrict__ H,
                               const float* __restrict__ Wr0,
                               const float* __restrict__ br0,
                               const float* __restrict__ Wr1,
                               const float* __restrict__ br1,
                               const int* __restrict__ batch,
                               float* __restrict__ gsum,
                               float* __restrict__ gcnt, int n) {
    __shared__ float Ws[64 * 32];
    __shared__ float w1s[32];
    for (int i = threadIdx.x; i < 64 * 32; i += blockDim.x) Ws[i] = Wr0[i];
    if (threadIdx.x < 32) w1s[threadIdx.x] = Wr1[threadIdx.x];
    __syncthreads();
    int r = blockIdx.x * blockDim.x + threadIdx.x;
    int lane = threadIdx.x & 63;
    float sv = 0.0f;
    int g = -1;
    if (r < n) {
        float h[64];
        const float4* hr = (const float4*)(H + (size_t)r * 64);
#pragma unroll
        for (int i = 0; i < 16; ++i) {
            float4 v = hr[i];
            h[4 * i + 0] = v.x; h[4 * i + 1] = v.y;
            h[4 * i + 2] = v.z; h[4 * i + 3] = v.w;
        }
        float ssum = 0.0f;
#pragma unroll 1
        for (int jg = 0; jg < 8; ++jg) {
            float a0 = br0[jg * 4 + 0], a1 = br0[jg * 4 + 1];
            float a2 = br0[jg * 4 + 2], a3 = br0[jg * 4 + 3];
#pragma unroll
            for (int k = 0; k < 64; ++k) {
                const float4 wv = *(const float4*)&Ws[k * 32 + jg * 4];
                a0 = fmaf(h[k], wv.x, a0);
                a1 = fmaf(h[k], wv.y, a1);
                a2 = fmaf(h[k], wv.z, a2);
                a3 = fmaf(h[k], wv.w, a3);
            }
            a0 = fmaxf(a0, 0.0f); a1 = fmaxf(a1, 0.0f);
            a2 = fmaxf(a2, 0.0f); a3 = fmaxf(a3, 0.0f);
            ssum += a0 * w1s[jg * 4 + 0] + a1 * w1s[jg * 4 + 1] +
                    a2 * w1s[jg * 4 + 2] + a3 * w1s[jg * 4 + 3];
        }
        sv = ssum + br1[0];
        g = batch[r];
    }
    float c = (r < n) ? 1.0f : 0.0f;
#pragma unroll
    for (int off = 1; off < 64; off <<= 1) {
        int   og = __shfl_down(g, off);
        float ov = __shfl_down(sv, off);
        float oc = __shfl_down(c, off);
        if ((lane + off) < 64 && og == g) { sv += ov; c += oc; }
    }
    int gprev = __shfl_up(g, 1);
    bool head = (lane == 0) || (gprev != g);
    if (head && g >= 0) {
        atomicAdd(&gsum[g], sv);
        atomicAdd(&gcnt[g], c);
    }
}

__global__ void pool_fin_kernel(const float* __restrict__ gsum,
                                const float* __restrict__ gcnt,
                                float* __restrict__ out, int ng) {
    int g = blockIdx.x * blockDim.x + threadIdx.x;
    if (g < ng) out[g] = gsum[g] / fmaxf(gcnt[g], 1.0f);
}

extern "C" void kernel_launch(void* const* d_in, const int* in_sizes, int n_in,
                              void* d_out, int out_size, void* d_ws, size_t ws_size,
                              hipStream_t stream) {
    const float* x    = (const float*)d_in[0];
    const int*   ei   = (const int*)d_in[1];
    const float* ew   = (const float*)d_in[2];
    const int*   batch= (const int*)d_in[3];
    const float* W0   = (const float*)d_in[4];
    const float* b0   = (const float*)d_in[5];
    const float* W1   = (const float*)d_in[6];
    const float* b1   = (const float*)d_in[7];
    const float* W2   = (const float*)d_in[8];
    const float* b2   = (const float*)d_in[9];
    const float* Wr0  = (const float*)d_in[10];
    const float* br0  = (const float*)d_in[11];
    const float* Wr1  = (const float*)d_in[12];
    const float* br1  = (const float*)d_in[13];
    float* out = (float*)d_out;

    int n  = in_sizes[0] / 64;   // 100000
    int ne = in_sizes[1] / 2;    // 1600000
    int ng = out_size;           // 256
    const int* srcv = ei;
    const int* dstv = ei + ne;
    int nbk = (n + 255) >> 8;    // 391

    char* ws = (char*)d_ws;
    size_t off = 0;
    auto alloc = [&](size_t bytes) {
        void* p = ws + off;
        off += (bytes + 255) & ~(size_t)255;
        return p;
    };
    float* Ts     = (float*)alloc((size_t)n * 64 * sizeof(float));
    float* A      = (float*)alloc((size_t)n * 64 * sizeof(float));
    float* dinv   = (float*)alloc((size_t)n * sizeof(float));
    int*   cnt    = (int*)alloc((size_t)n * sizeof(int));
    int*   rptr   = (int*)alloc((size_t)n * sizeof(int));
    int*   bcnt   = (int*)alloc(520 * sizeof(int));
    int*   bbase  = (int*)alloc(520 * sizeof(int));
    int*   gcur   = (int*)alloc(520 * sizeof(int));
    int2*  csr    = (int2*)alloc((size_t)ne * sizeof(int2));
    float* gsum   = (float*)alloc((size_t)ng * sizeof(float));
    float* gcnt   = (float*)alloc((size_t)ng * sizeof(float));
    // packed aliases Ts: consumed by bucket_build before first gemm writes Ts.
    int2*  packed = (int2*)Ts;
    (void)ws_size;

    hipMemsetAsync(bcnt, 0, 520 * sizeof(int), stream);
    hipMemsetAsync(gsum, 0, (size_t)ng * sizeof(float), stream);
    hipMemsetAsync(gcnt, 0, (size_t)ng * sizeof(float), stream);

    hist_kernel<<<256, 256, 0, stream>>>(dstv, bcnt, ne);
    bscan_kernel<<<1, 512, 0, stream>>>(bcnt, bbase, gcur, nbk, ne);
    scatterB_kernel<<<200, 256, 0, stream>>>(srcv, dstv, ew, gcur, packed, ne);
    bucket_build_kernel<<<nbk, 256, 0, stream>>>(packed, bbase, rptr, cnt,
                                                 dinv, csr, n);

    const int gemm_blocks = 2048;
    unsigned gat_blocks = (unsigned)(((size_t)n * 64 + 255) / 256);

    // gemm0: Ts = x@W0*dinv
    gemm_rl_kernel<false><<<gemm_blocks, 256, 0, stream>>>(x, W0, dinv, Ts, n);
    // layer1: A-buf <- relu(gather(Ts)+b0) @ W1 * dinv   (A1 never stored)
    fgather_kernel<<<gat_blocks, 256, 0, stream>>>(csr, rptr, cnt, dinv, b0,
                                                   Ts, W1, A, n);
    // layer2: Ts <- relu(gather(A-buf)+b1) @ W2 * dinv   (A2 never stored)
    fgather_kernel<<<gat_blocks, 256, 0, stream>>>(csr, rptr, cnt, dinv, b1,
                                                   A, W2, Ts, n);
    // layer3: A <- gather(Ts)+b2   (final conv output)
    gather_kernel<<<gat_blocks, 256, 0, stream>>>(csr, rptr, cnt, dinv, b2,
                                                  Ts, A, n);

    readout_kernel<<<(n + 255) / 256, 256, 0, stream>>>(A, Wr0, br0, Wr1, br1,
                                                        batch, gsum, gcnt, n);
    pool_fin_kernel<<<(ng + 255) / 256, 256, 0, stream>>>(gsum, gcnt, out, ng);
}

// Round 15
// 355.929 us; speedup vs baseline: 7.0091x; 1.0106x over previous
//
#include <hip/hip_runtime.h>

// ---------------------------------------------------------------------------
// Petri_GCN: 3x GCNConv(64->64) + MLP readout (64->32->1) + segment-mean pool
// All fp32 (abs threshold forbids bf16/MFMA; no fp32 MFMA on CDNA4).
// R1: CSR-by-dst + gather. R2: segmented readout atomics; float4 gather.
// R3: Ts=(X@W)*dinv epilogue; gather pure-write. R5: bucketed CSR build.
// R8-R12: gemm shape search; spill lessons (scratch = WRITE_SIZE blowup).
// R13: readlane-broadcast gemm (~35us); gather is L2-miss-BW-bound.
// R14: fused gather+next-gemm (fgather). Net -13us/layer, NOT the predicted
//     -30: epilogue = ONE 64-FMA serial chain per wave -> waves stall ~40%
//     of life in it, VMEM issue drops (BW 3.5->2.6 TB/s). Additive tail.
// R15: (1) fgather epilogue split into 4 indep FMA chains (dep 256->64cyc);
//     (2) readout MLP fused into final gather (rgather, 4-chain from the
//     start): A never materialized, readout kernel deleted; tiny segmented
//     reduce over per-node scalars replaces it.
// ---------------------------------------------------------------------------

#define NBK 391          // ceil(100000/256) buckets; arrays padded to 512

__device__ __forceinline__ float bcastf(float v, int l) {
    return __int_as_float(__builtin_amdgcn_readlane(__float_as_int(v), l));
}

// LDS histogram of dst>>8, merged to global.
__global__ void hist_kernel(const int* __restrict__ dst,
                            int* __restrict__ bcnt, int ne) {
    __shared__ int h[512];
    for (int i = threadIdx.x; i < 512; i += blockDim.x) h[i] = 0;
    __syncthreads();
    int stride = gridDim.x * blockDim.x;
    for (int e = blockIdx.x * blockDim.x + threadIdx.x; e < ne; e += stride)
        atomicAdd(&h[dst[e] >> 8], 1);
    __syncthreads();
    for (int i = threadIdx.x; i < 512; i += blockDim.x)
        if (h[i]) atomicAdd(&bcnt[i], h[i]);
}

// One block: exclusive scan of bucket counts -> bbase[0..nb], seed gcur.
__global__ void bscan_kernel(const int* __restrict__ bcnt,
                             int* __restrict__ bbase,
                             int* __restrict__ gcur, int nb, int ne) {
    __shared__ int sh[512];
    int t = threadIdx.x;
    int v = (t < nb) ? bcnt[t] : 0;
    sh[t] = v;
    __syncthreads();
    for (int off = 1; off < 512; off <<= 1) {
        int u = (t >= off) ? sh[t - off] : 0;
        __syncthreads();
        sh[t] += u;
        __syncthreads();
    }
    if (t < nb) {
        int e = sh[t] - v;
        bbase[t] = e;
        gcur[t] = e;
    }
    if (t == 0) bbase[nb] = ne;
}

// Redistribute edges into bucket regions. packed = {(local8<<24)|src17, w}.
__global__ void scatterB_kernel(const int* __restrict__ src,
                                const int* __restrict__ dst,
                                const float* __restrict__ ew,
                                int* __restrict__ gcur,
                                int2* __restrict__ packed, int ne) {
    __shared__ int h[512];
    __shared__ int cur[512];
    int chunk = (ne + gridDim.x - 1) / gridDim.x;
    int e0 = blockIdx.x * chunk;
    int e1 = e0 + chunk; if (e1 > ne) e1 = ne;
    for (int i = threadIdx.x; i < 512; i += blockDim.x) h[i] = 0;
    __syncthreads();
    for (int e = e0 + threadIdx.x; e < e1; e += blockDim.x)
        atomicAdd(&h[dst[e] >> 8], 1);
    __syncthreads();
    for (int i = threadIdx.x; i < 512; i += blockDim.x)
        cur[i] = h[i] ? atomicAdd(&gcur[i], h[i]) : 0;
    __syncthreads();
    for (int e = e0 + threadIdx.x; e < e1; e += blockDim.x) {
        int d = dst[e];
        int pos = atomicAdd(&cur[d >> 8], 1);   // LDS atomic
        int2 v;
        v.x = ((d & 255) << 24) | src[e];       // src < 2^17, fits
        v.y = __float_as_int(ew[e]);
        packed[pos] = v;
    }
}

// One WG per bucket (256 nodes): count/scan/scatter in LDS, emit rptr/cnt/
// dinv + final CSR in the bucket's L2-hot window. No global atomics.
__global__ void bucket_build_kernel(const int2* __restrict__ packed,
                                    const int* __restrict__ bbase,
                                    int* __restrict__ rptr,
                                    int* __restrict__ cnt,
                                    float* __restrict__ dinv,
                                    int2* __restrict__ csr, int n) {
    __shared__ int cl[256];
    __shared__ int sc[256];
    __shared__ int cur[256];
    int b = blockIdx.x;
    int t = threadIdx.x;
    int node0 = b << 8;
    int nn = n - node0; if (nn > 256) nn = 256;
    int ebase = bbase[b];
    int m = bbase[b + 1] - ebase;
    cl[t] = 0;
    __syncthreads();
    for (int j = t; j < m; j += 256) {
        int local = ((unsigned)packed[ebase + j].x) >> 24;
        atomicAdd(&cl[local], 1);               // LDS atomic
    }
    __syncthreads();
    int c = cl[t];
    sc[t] = c;
    __syncthreads();
    for (int off = 1; off < 256; off <<= 1) {
        int u = (t >= off) ? sc[t - off] : 0;
        __syncthreads();
        sc[t] += u;
        __syncthreads();
    }
    int base = ebase + sc[t] - c;               // global CSR row start
    cur[t] = base;
    if (t < nn) {
        rptr[node0 + t] = base;
        cnt[node0 + t] = c;
    }
    __syncthreads();
    for (int j = t; j < m; j += 256) {
        int2 p = packed[ebase + j];
        int local = ((unsigned)p.x) >> 24;
        int pos = atomicAdd(&cur[local], 1);    // LDS atomic
        int2 v;
        v.x = p.x & 0x00FFFFFF;
        v.y = p.y;
        csr[pos] = v;
    }
    __syncthreads();
    if (t < nn) {
        float s = 0.0f;
        for (int j = base; j < base + c; ++j)
            s += __int_as_float(csr[j].y);
        dinv[node0 + t] = 1.0f / sqrtf(s + 1.0f);
    }
}

// GEMM via readlane broadcast (R13, proven).
template <bool RELU>
__global__ void __launch_bounds__(256, 4)
gemm_rl_kernel(const float* __restrict__ X, const float* W,
               const float* __restrict__ dinv, float* __restrict__ Ts,
               int n) {
    __shared__ float Wl[4096];
    {
        const float4* Wv = (const float4*)W;
        float4* Lv = (float4*)Wl;
        for (int i = threadIdx.x; i < 1024; i += 256) Lv[i] = Wv[i];
    }
    __syncthreads();
    int lane = threadIdx.x & 63;
    int wid  = (blockIdx.x * blockDim.x + threadIdx.x) >> 6;
    int nw   = (gridDim.x * blockDim.x) >> 6;
    int lrow = lane >> 4;
    int lcol = (lane & 15) * 4;
    for (int r0 = wid * 4; r0 + 4 <= n; r0 += nw * 4) {
        float4 xv = *(const float4*)&X[(size_t)(r0 + lrow) * 64 + lcol];
        if (RELU) {
            xv.x = fmaxf(xv.x, 0.f); xv.y = fmaxf(xv.y, 0.f);
            xv.z = fmaxf(xv.z, 0.f); xv.w = fmaxf(xv.w, 0.f);
        }
        float a0 = 0.f, a1 = 0.f, a2 = 0.f, a3 = 0.f;
#pragma unroll
        for (int k4 = 0; k4 < 16; ++k4) {
            float w0 = Wl[(4 * k4 + 0) * 64 + lane];
            float w1 = Wl[(4 * k4 + 1) * 64 + lane];
            float w2 = Wl[(4 * k4 + 2) * 64 + lane];
            float w3 = Wl[(4 * k4 + 3) * 64 + lane];
            a0 = fmaf(bcastf(xv.x, k4), w0, a0);
            a0 = fmaf(bcastf(xv.y, k4), w1, a0);
            a0 = fmaf(bcastf(xv.z, k4), w2, a0);
            a0 = fmaf(bcastf(xv.w, k4), w3, a0);
            a1 = fmaf(bcastf(xv.x, 16 + k4), w0, a1);
            a1 = fmaf(bcastf(xv.y, 16 + k4), w1, a1);
            a1 = fmaf(bcastf(xv.z, 16 + k4), w2, a1);
            a1 = fmaf(bcastf(xv.w, 16 + k4), w3, a1);
            a2 = fmaf(bcastf(xv.x, 32 + k4), w0, a2);
            a2 = fmaf(bcastf(xv.y, 32 + k4), w1, a2);
            a2 = fmaf(bcastf(xv.z, 32 + k4), w2, a2);
            a2 = fmaf(bcastf(xv.w, 32 + k4), w3, a2);
            a3 = fmaf(bcastf(xv.x, 48 + k4), w0, a3);
            a3 = fmaf(bcastf(xv.y, 48 + k4), w1, a3);
            a3 = fmaf(bcastf(xv.z, 48 + k4), w2, a3);
            a3 = fmaf(bcastf(xv.w, 48 + k4), w3, a3);
        }
        Ts[(size_t)(r0 + 0) * 64 + lane] = a0 * dinv[r0 + 0];
        Ts[(size_t)(r0 + 1) * 64 + lane] = a1 * dinv[r0 + 1];
        Ts[(size_t)(r0 + 2) * 64 + lane] = a2 * dinv[r0 + 2];
        Ts[(size_t)(r0 + 3) * 64 + lane] = a3 * dinv[r0 + 3];
    }
    if (wid == 0) {
        for (int r = (n & ~3); r < n; ++r) {
            const float4* xr = (const float4*)(X + (size_t)r * 64);
            float acc = 0.f;
#pragma unroll
            for (int k4 = 0; k4 < 16; ++k4) {
                float4 a = xr[k4];
                if (RELU) {
                    a.x = fmaxf(a.x, 0.f); a.y = fmaxf(a.y, 0.f);
                    a.z = fmaxf(a.z, 0.f); a.w = fmaxf(a.w, 0.f);
                }
                acc = fmaf(a.x, Wl[(4 * k4 + 0) * 64 + lane], acc);
                acc = fmaf(a.y, Wl[(4 * k4 + 1) * 64 + lane], acc);
                acc = fmaf(a.z, Wl[(4 * k4 + 2) * 64 + lane], acc);
                acc = fmaf(a.w, Wl[(4 * k4 + 3) * 64 + lane], acc);
            }
            Ts[(size_t)r * 64 + lane] = acc * dinv[r];
        }
    }
}

// Fused gather + next-layer gemm (R14) with 4-chain epilogue (R15):
// x/y/z/w broadcast terms go to independent accumulators -> dep chain
// 256 -> ~64 cycles, waves return to issuing memory sooner.
__global__ void __launch_bounds__(256, 4)
fgather_kernel(const int2* __restrict__ csr,
               const int* __restrict__ rptr,
               const int* __restrict__ cnt,
               const float* __restrict__ dinv,
               const float* __restrict__ b,
               const float* __restrict__ Ts_in,
               const float* Wn,
               float* __restrict__ Ts_out, int n) {
    __shared__ float Wl[4096];
    {
        const float4* Wv = (const float4*)Wn;
        float4* Lv = (float4*)Wl;
        for (int i = threadIdx.x; i < 1024; i += 256) Lv[i] = Wv[i];
    }
    __syncthreads();
    int lane = threadIdx.x & 63;
    int r = (int)(((size_t)blockIdx.x * blockDim.x + threadIdx.x) >> 6);
    if (r >= n) return;
    int sub = lane >> 4;
    int cl  = lane & 15;
    int start = rptr[r];
    int m = cnt[r];
    float4 a0 = {0.f, 0.f, 0.f, 0.f};
    float4 a1 = {0.f, 0.f, 0.f, 0.f};
    float4 a2 = {0.f, 0.f, 0.f, 0.f};
    float4 a3 = {0.f, 0.f, 0.f, 0.f};
    int j = sub;
    for (; j + 12 < m; j += 16) {
        int2 e0 = csr[start + j];
        int2 e1 = csr[start + j + 4];
        int2 e2 = csr[start + j + 8];
        int2 e3 = csr[start + j + 12];
        float w0 = __int_as_float(e0.y);
        float w1 = __int_as_float(e1.y);
        float w2 = __int_as_float(e2.y);
        float w3 = __int_as_float(e3.y);
        float4 t0 = *(const float4*)&Ts_in[(size_t)e0.x * 64 + cl * 4];
        float4 t1 = *(const float4*)&Ts_in[(size_t)e1.x * 64 + cl * 4];
        float4 t2 = *(const float4*)&Ts_in[(size_t)e2.x * 64 + cl * 4];
        float4 t3 = *(const float4*)&Ts_in[(size_t)e3.x * 64 + cl * 4];
        a0.x = fmaf(t0.x, w0, a0.x); a0.y = fmaf(t0.y, w0, a0.y);
        a0.z = fmaf(t0.z, w0, a0.z); a0.w = fmaf(t0.w, w0, a0.w);
        a1.x = fmaf(t1.x, w1, a1.x); a1.y = fmaf(t1.y, w1, a1.y);
        a1.z = fmaf(t1.z, w1, a1.z); a1.w = fmaf(t1.w, w1, a1.w);
        a2.x = fmaf(t2.x, w2, a2.x); a2.y = fmaf(t2.y, w2, a2.y);
        a2.z = fmaf(t2.z, w2, a2.z); a2.w = fmaf(t2.w, w2, a2.w);
        a3.x = fmaf(t3.x, w3, a3.x); a3.y = fmaf(t3.y, w3, a3.y);
        a3.z = fmaf(t3.z, w3, a3.z); a3.w = fmaf(t3.w, w3, a3.w);
    }
    for (; j < m; j += 4) {
        int2 e0 = csr[start + j];
        float w0 = __int_as_float(e0.y);
        float4 t0 = *(const float4*)&Ts_in[(size_t)e0.x * 64 + cl * 4];
        a0.x = fmaf(t0.x, w0, a0.x); a0.y = fmaf(t0.y, w0, a0.y);
        a0.z = fmaf(t0.z, w0, a0.z); a0.w = fmaf(t0.w, w0, a0.w);
    }
    a0.x += a1.x + a2.x + a3.x;
    a0.y += a1.y + a2.y + a3.y;
    a0.z += a1.z + a2.z + a3.z;
    a0.w += a1.w + a2.w + a3.w;
#pragma unroll
    for (int off = 16; off < 64; off <<= 1) {
        a0.x += __shfl_xor(a0.x, off);
        a0.y += __shfl_xor(a0.y, off);
        a0.z += __shfl_xor(a0.z, off);
        a0.w += __shfl_xor(a0.w, off);
    }
    float dv = dinv[r];
    float4 ts = *(const float4*)&Ts_in[(size_t)r * 64 + cl * 4];
    float4 bb = *(const float4*)&b[cl * 4];
    float tx = fmaxf(fmaf(dv, a0.x + ts.x, bb.x), 0.f);
    float ty = fmaxf(fmaf(dv, a0.y + ts.y, bb.y), 0.f);
    float tz = fmaxf(fmaf(dv, a0.z + ts.z, bb.z), 0.f);
    float tw = fmaxf(fmaf(dv, a0.w + ts.w, bb.w), 0.f);
    // fused gemm, 4 independent chains (R15)
    float c0 = 0.f, c1 = 0.f, c2 = 0.f, c3 = 0.f;
#pragma unroll
    for (int q = 0; q < 16; ++q) {
        c0 = fmaf(bcastf(tx, q), Wl[(4 * q + 0) * 64 + lane], c0);
        c1 = fmaf(bcastf(ty, q), Wl[(4 * q + 1) * 64 + lane], c1);
        c2 = fmaf(bcastf(tz, q), Wl[(4 * q + 2) * 64 + lane], c2);
        c3 = fmaf(bcastf(tw, q), Wl[(4 * q + 3) * 64 + lane], c3);
    }
    Ts_out[(size_t)r * 64 + lane] = ((c0 + c1) + (c2 + c3)) * dv;
}

// Final layer: gather + readout MLP fused. After butterfly all lanes hold
// the full row sums -> A[r] (no relu, last GCN layer) lives in registers
// only. Lane computes hidden_(lane&31) via 4 FMA chains (Wr0 in LDS),
// relu, *Wr1, 5-step shfl reduce; lane 0 writes per-node scalar sv.
__global__ void __launch_bounds__(256, 4)
rgather_kernel(const int2* __restrict__ csr,
               const int* __restrict__ rptr,
               const int* __restrict__ cnt,
               const float* __restrict__ dinv,
               const float* __restrict__ b,
               const float* __restrict__ Ts,
               const float* Wr0, const float* br0,
               const float* Wr1, const float* br1,
               float* __restrict__ svbuf, int n) {
    __shared__ float Wl[64 * 32];
    __shared__ float w1s[32];
    __shared__ float b0s[32];
    {
        const float4* Wv = (const float4*)Wr0;
        float4* Lv = (float4*)Wl;
        for (int i = threadIdx.x; i < 512; i += 256) Lv[i] = Wv[i];
        if (threadIdx.x < 32) {
            w1s[threadIdx.x] = Wr1[threadIdx.x];
            b0s[threadIdx.x] = br0[threadIdx.x];
        }
    }
    __syncthreads();
    int lane = threadIdx.x & 63;
    int r = (int)(((size_t)blockIdx.x * blockDim.x + threadIdx.x) >> 6);
    if (r >= n) return;
    int sub = lane >> 4;
    int cl  = lane & 15;
    int start = rptr[r];
    int m = cnt[r];
    float4 a0 = {0.f, 0.f, 0.f, 0.f};
    float4 a1 = {0.f, 0.f, 0.f, 0.f};
    float4 a2 = {0.f, 0.f, 0.f, 0.f};
    float4 a3 = {0.f, 0.f, 0.f, 0.f};
    int j = sub;
    for (; j + 12 < m; j += 16) {
        int2 e0 = csr[start + j];
        int2 e1 = csr[start + j + 4];
        int2 e2 = csr[start + j + 8];
        int2 e3 = csr[start + j + 12];
        float w0 = __int_as_float(e0.y);
        float w1 = __int_as_float(e1.y);
        float w2 = __int_as_float(e2.y);
        float w3 = __int_as_float(e3.y);
        float4 t0 = *(const float4*)&Ts[(size_t)e0.x * 64 + cl * 4];
        float4 t1 = *(const float4*)&Ts[(size_t)e1.x * 64 + cl * 4];
        float4 t2 = *(const float4*)&Ts[(size_t)e2.x * 64 + cl * 4];
        float4 t3 = *(const float4*)&Ts[(size_t)e3.x * 64 + cl * 4];
        a0.x = fmaf(t0.x, w0, a0.x); a0.y = fmaf(t0.y, w0, a0.y);
        a0.z = fmaf(t0.z, w0, a0.z); a0.w = fmaf(t0.w, w0, a0.w);
        a1.x = fmaf(t1.x, w1, a1.x); a1.y = fmaf(t1.y, w1, a1.y);
        a1.z = fmaf(t1.z, w1, a1.z); a1.w = fmaf(t1.w, w1, a1.w);
        a2.x = fmaf(t2.x, w2, a2.x); a2.y = fmaf(t2.y, w2, a2.y);
        a2.z = fmaf(t2.z, w2, a2.z); a2.w = fmaf(t2.w, w2, a2.w);
        a3.x = fmaf(t3.x, w3, a3.x); a3.y = fmaf(t3.y, w3, a3.y);
        a3.z = fmaf(t3.z, w3, a3.z); a3.w = fmaf(t3.w, w3, a3.w);
    }
    for (; j < m; j += 4) {
        int2 e0 = csr[start + j];
        float w0 = __int_as_float(e0.y);
        float4 t0 = *(const float4*)&Ts[(size_t)e0.x * 64 + cl * 4];
        a0.x = fmaf(t0.x, w0, a0.x); a0.y = fmaf(t0.y, w0, a0.y);
        a0.z = fmaf(t0.z, w0, a0.z); a0.w = fmaf(t0.w, w0, a0.w);
    }
    a0.x += a1.x + a2.x + a3.x;
    a0.y += a1.y + a2.y + a3.y;
    a0.z += a1.z + a2.z + a3.z;
    a0.w += a1.w + a2.w + a3.w;
#pragma unroll
    for (int off = 16; off < 64; off <<= 1) {
        a0.x += __shfl_xor(a0.x, off);
        a0.y += __shfl_xor(a0.y, off);
        a0.z += __shfl_xor(a0.z, off);
        a0.w += __shfl_xor(a0.w, off);
    }
    float dv = dinv[r];
    float4 ts = *(const float4*)&Ts[(size_t)r * 64 + cl * 4];
    float4 bb = *(const float4*)&b[cl * 4];
    float tx = fmaf(dv, a0.x + ts.x, bb.x);   // A row values (no relu)
    float ty = fmaf(dv, a0.y + ts.y, bb.y);
    float tz = fmaf(dv, a0.z + ts.z, bb.z);
    float tw = fmaf(dv, a0.w + ts.w, bb.w);
    // hidden_(lane&31), 4 chains; upper 32 lanes duplicate (same-addr LDS)
    int hj = lane & 31;
    float c0 = 0.f, c1 = 0.f, c2 = 0.f, c3 = 0.f;
#pragma unroll
    for (int q = 0; q < 16; ++q) {
        c0 = fmaf(bcastf(tx, q), Wl[(4 * q + 0) * 32 + hj], c0);
        c1 = fmaf(bcastf(ty, q), Wl[(4 * q + 1) * 32 + hj], c1);
        c2 = fmaf(bcastf(tz, q), Wl[(4 * q + 2) * 32 + hj], c2);
        c3 = fmaf(bcastf(tw, q), Wl[(4 * q + 3) * 32 + hj], c3);
    }
    float h = fmaxf(((c0 + c1) + (c2 + c3)) + b0s[hj], 0.f);
    float p = h * w1s[hj];
#pragma unroll
    for (int off = 1; off < 32; off <<= 1) p += __shfl_xor(p, off);
    if (lane == 0) svbuf[r] = p + br1[0];
}

// Wave-segmented reduce of per-node scalars (batch sorted).
__global__ void segpool_kernel(const float* __restrict__ svbuf,
                               const int* __restrict__ batch,
                               float* __restrict__ gsum,
                               float* __restrict__ gcnt, int n) {
    int r = blockIdx.x * blockDim.x + threadIdx.x;
    int lane = threadIdx.x & 63;
    float sv = 0.0f;
    int g = -1;
    if (r < n) { sv = svbuf[r]; g = batch[r]; }
    float c = (r < n) ? 1.0f : 0.0f;
#pragma unroll
    for (int off = 1; off < 64; off <<= 1) {
        int   og = __shfl_down(g, off);
        float ov = __shfl_down(sv, off);
        float oc = __shfl_down(c, off);
        if ((lane + off) < 64 && og == g) { sv += ov; c += oc; }
    }
    int gprev = __shfl_up(g, 1);
    bool head = (lane == 0) || (gprev != g);
    if (head && g >= 0) {
        atomicAdd(&gsum[g], sv);
        atomicAdd(&gcnt[g], c);
    }
}

__global__ void pool_fin_kernel(const float* __restrict__ gsum,
                                const float* __restrict__ gcnt,
                                float* __restrict__ out, int ng) {
    int g = blockIdx.x * blockDim.x + threadIdx.x;
    if (g < ng) out[g] = gsum[g] / fmaxf(gcnt[g], 1.0f);
}

extern "C" void kernel_launch(void* const* d_in, const int* in_sizes, int n_in,
                              void* d_out, int out_size, void* d_ws, size_t ws_size,
                              hipStream_t stream) {
    const float* x    = (const float*)d_in[0];
    const int*   ei   = (const int*)d_in[1];
    const float* ew   = (const float*)d_in[2];
    const int*   batch= (const int*)d_in[3];
    const float* W0   = (const float*)d_in[4];
    const float* b0   = (const float*)d_in[5];
    const float* W1   = (const float*)d_in[6];
    const float* b1   = (const float*)d_in[7];
    const float* W2   = (const float*)d_in[8];
    const float* b2   = (const float*)d_in[9];
    const float* Wr0  = (const float*)d_in[10];
    const float* br0  = (const float*)d_in[11];
    const float* Wr1  = (const float*)d_in[12];
    const float* br1  = (const float*)d_in[13];
    float* out = (float*)d_out;

    int n  = in_sizes[0] / 64;   // 100000
    int ne = in_sizes[1] / 2;    // 1600000
    int ng = out_size;           // 256
    const int* srcv = ei;
    const int* dstv = ei + ne;
    int nbk = (n + 255) >> 8;    // 391

    char* ws = (char*)d_ws;
    size_t off = 0;
    auto alloc = [&](size_t bytes) {
        void* p = ws + off;
        off += (bytes + 255) & ~(size_t)255;
        return p;
    };
    float* Ts     = (float*)alloc((size_t)n * 64 * sizeof(float));
    float* A      = (float*)alloc((size_t)n * 64 * sizeof(float));
    float* dinv   = (float*)alloc((size_t)n * sizeof(float));
    float* svbuf  = (float*)alloc((size_t)n * sizeof(float));
    int*   cnt    = (int*)alloc((size_t)n * sizeof(int));
    int*   rptr   = (int*)alloc((size_t)n * sizeof(int));
    int*   bcnt   = (int*)alloc(520 * sizeof(int));
    int*   bbase  = (int*)alloc(520 * sizeof(int));
    int*   gcur   = (int*)alloc(520 * sizeof(int));
    int2*  csr    = (int2*)alloc((size_t)ne * sizeof(int2));
    float* gsum   = (float*)alloc((size_t)ng * sizeof(float));
    float* gcnt   = (float*)alloc((size_t)ng * sizeof(float));
    // packed aliases Ts: consumed by bucket_build before first gemm writes Ts.
    int2*  packed = (int2*)Ts;
    (void)ws_size;

    hipMemsetAsync(bcnt, 0, 520 * sizeof(int), stream);
    hipMemsetAsync(gsum, 0, (size_t)ng * sizeof(float), stream);
    hipMemsetAsync(gcnt, 0, (size_t)ng * sizeof(float), stream);

    hist_kernel<<<256, 256, 0, stream>>>(dstv, bcnt, ne);
    bscan_kernel<<<1, 512, 0, stream>>>(bcnt, bbase, gcur, nbk, ne);
    scatterB_kernel<<<200, 256, 0, stream>>>(srcv, dstv, ew, gcur, packed, ne);
    bucket_build_kernel<<<nbk, 256, 0, stream>>>(packed, bbase, rptr, cnt,
                                                 dinv, csr, n);

    const int gemm_blocks = 2048;
    unsigned gat_blocks = (unsigned)(((size_t)n * 64 + 255) / 256);

    // gemm0: Ts = x@W0*dinv
    gemm_rl_kernel<false><<<gemm_blocks, 256, 0, stream>>>(x, W0, dinv, Ts, n);
    // layer1: A-buf <- relu(gather(Ts)+b0) @ W1 * dinv
    fgather_kernel<<<gat_blocks, 256, 0, stream>>>(csr, rptr, cnt, dinv, b0,
                                                   Ts, W1, A, n);
    // layer2: Ts <- relu(gather(A-buf)+b1) @ W2 * dinv
    fgather_kernel<<<gat_blocks, 256, 0, stream>>>(csr, rptr, cnt, dinv, b1,
                                                   A, W2, Ts, n);
    // layer3 + readout: sv[r] = MLP(gather(Ts)+b2)  (A never materialized)
    rgather_kernel<<<gat_blocks, 256, 0, stream>>>(csr, rptr, cnt, dinv, b2,
                                                   Ts, Wr0, br0, Wr1, br1,
                                                   svbuf, n);
    segpool_kernel<<<(n + 255) / 256, 256, 0, stream>>>(svbuf, batch,
                                                        gsum, gcnt, n);
    pool_fin_kernel<<<(ng + 255) / 256, 256, 0, stream>>>(gsum, gcnt, out, ng);
}